// Round 5
// baseline (639.692 us; speedup 1.0000x reference)
//
#include <hip/hip_runtime.h>
#include <hip/hip_bf16.h>
#include <math.h>

#define TT     365
#define BT     23360      // 64*365
#define NPOS   425

typedef __hip_bfloat16 bf16;
typedef __attribute__((ext_vector_type(8))) short s16x8;
typedef __attribute__((ext_vector_type(4))) float f32x4;

__device__ __forceinline__ float b2f(bf16 v) { return __bfloat162float(v); }
__device__ __forceinline__ bf16  f2b(float v) { return __float2bfloat16(v); }
__device__ __forceinline__ float u2f(unsigned u) { return __uint_as_float(u); }

// ---------------- fused prep: zero stats/pooled, cast x, split-cast weights, pos table (f32) -----
// weight segments in whi/wlo: w2@0(8192) w3@8192(32768) wi@40960(65536) wq@106496(32768) wk@139264(32768)
__global__ __launch_bounds__(256) void prep_kernel(
    float* __restrict__ stats, float* __restrict__ pooled,
    const float* __restrict__ x, bf16* __restrict__ xb,
    const float* __restrict__ w2, const float* __restrict__ w3, const float* __restrict__ wi,
    const float* __restrict__ wq, const float* __restrict__ wk,
    bf16* __restrict__ whi, bf16* __restrict__ wlo, float* __restrict__ tab)
{
    int i = blockIdx.x * 256 + threadIdx.x;
    if (i < 2048)   { stats[i] = 0.f; return; }  i -= 2048;
    if (i < 16384)  { pooled[i] = 0.f; return; } i -= 16384;
    if (i < 233600) { xb[i] = f2b(x[i]); return; } i -= 233600;
    if (i < 172032) {
        float w;
        if      (i < 8192)   w = w2[i];
        else if (i < 40960)  w = w3[i - 8192];
        else if (i < 106496) w = wi[i - 40960];
        else if (i < 139264) w = wq[i - 106496];
        else                 w = wk[i - 139264];
        bf16 h = f2b(w);
        whi[i] = h;
        wlo[i] = f2b(w - b2f(h));
        return;
    } i -= 172032;
    if (i < 108800) {
        int c = i & 255, p = i >> 8;
        float e = (float)(2 * (c >> 1)) * (1.f / 256.f);
        // 1000^-e = exp2(-e*log2(1000))
        float ang = (float)p * exp2f(-e * 9.96578428466209f);
        tab[i] = (c & 1) ? cosf(ang) : sinf(ang);
    }
}

// ---------------- L1 scalar GEMM (K=10): Y[M,64](bf16) = A(bf16)@W(f32)^T + b; fused BN stats ----
__global__ __launch_bounds__(256) void gemm_l1_kernel(
    const bf16* __restrict__ A,
    const float* __restrict__ W, const float* __restrict__ bias,
    bf16* __restrict__ Y, float* __restrict__ stats)
{
    const int K = 10;
    const int t  = threadIdx.x;
    const int tx = t & 15, ty = t >> 4;
    const int row0 = blockIdx.x * 64;
    __shared__ float As[64][17];
    __shared__ float Ws[16][65];
    __shared__ float red_s[4][64];
    __shared__ float red_q[4][64];
    float acc[4][4];
#pragma unroll
    for (int rr = 0; rr < 4; ++rr)
#pragma unroll
        for (int cc = 0; cc < 4; ++cc) acc[rr][cc] = 0.f;
    {
#pragma unroll
        for (int i = 0; i < 4; ++i) {
            int idx = t + i * 256, r = idx >> 4, c = idx & 15;
            As[r][c] = (c < K) ? b2f(A[(size_t)(row0 + r) * K + c]) : 0.f;
        }
#pragma unroll
        for (int i = 0; i < 4; ++i) {
            int idx = t + i * 256, c = idx >> 4, kk = idx & 15;
            Ws[kk][c] = (kk < K) ? W[(size_t)c * K + kk] : 0.f;
        }
        __syncthreads();
#pragma unroll
        for (int kk = 0; kk < 10; ++kk) {
            float a[4];
#pragma unroll
            for (int rr = 0; rr < 4; ++rr) a[rr] = As[ty * 4 + rr][kk];
#pragma unroll
            for (int cc = 0; cc < 4; ++cc) {
                float w = Ws[kk][cc * 16 + tx];
#pragma unroll
                for (int rr = 0; rr < 4; ++rr) acc[rr][cc] = fmaf(a[rr], w, acc[rr][cc]);
            }
        }
    }
    float s_cc[4], q_cc[4];
#pragma unroll
    for (int cc = 0; cc < 4; ++cc) { s_cc[cc] = 0.f; q_cc[cc] = 0.f; }
#pragma unroll
    for (int rr = 0; rr < 4; ++rr) {
        int row = row0 + ty * 4 + rr;
#pragma unroll
        for (int cc = 0; cc < 4; ++cc) {
            int col = cc * 16 + tx;
            float v = acc[rr][cc] + bias[col];
            Y[(size_t)row * 64 + col] = f2b(v);
            s_cc[cc] += v; q_cc[cc] += v * v;
        }
    }
    int w = t >> 6;
#pragma unroll
    for (int cc = 0; cc < 4; ++cc) {
        float s = s_cc[cc], q = q_cc[cc];
        s += __shfl_xor(s, 16); q += __shfl_xor(q, 16);
        s += __shfl_xor(s, 32); q += __shfl_xor(q, 32);
        if ((t & 63) < 16) { red_s[w][cc * 16 + tx] = s; red_q[w][cc * 16 + tx] = q; }
    }
    __syncthreads();
    if (t < 64) {
        float s = red_s[0][t] + red_s[1][t] + red_s[2][t] + red_s[3][t];
        float q = red_q[0][t] + red_q[1][t] + red_q[2][t] + red_q[3][t];
        atomicAdd(&stats[t], s);
        atomicAdd(&stats[256 + t], q);
    }
}

// ---------------- MFMA GEMM: 64 rows x 64 cols per block (4 waves x 16 rows); hi/lo bf16 W -------
// grid (M/64, N/64). A-frag A[m=lane&15][k=quad*8+j]; B-frag W[n][k]; C col=lane&15,row=quad*4+r.
__global__ __launch_bounds__(256) void mfma_gemm(
    const bf16* __restrict__ A, int K,
    const bf16* __restrict__ Whi, const bf16* __restrict__ Wlo,
    const float* __restrict__ bias,
    bf16* __restrict__ Y, int ldY, float* __restrict__ stats)
{
    __shared__ float red_s[4][64];
    __shared__ float red_q[4][64];
    const int t = threadIdx.x, wave = t >> 6, lane = t & 63;
    const int n16 = lane & 15, quad = lane >> 4;
    const int m0 = blockIdx.x * 64 + wave * 16;
    const int col0 = blockIdx.y * 64;
    f32x4 acc[4];
    f32x4 zero = {0.f, 0.f, 0.f, 0.f};
#pragma unroll
    for (int ct = 0; ct < 4; ++ct) acc[ct] = zero;
    const bf16* Ap = A + (size_t)(m0 + n16) * K + quad * 8;
    const size_t wbase = (size_t)(col0 + n16) * K + quad * 8;
    for (int k0 = 0; k0 < K; k0 += 32) {
        s16x8 af = *(const s16x8*)(Ap + k0);
#pragma unroll
        for (int ct = 0; ct < 4; ++ct) {
            size_t wo = wbase + (size_t)ct * 16 * K + k0;
            s16x8 bl = *(const s16x8*)(Wlo + wo);
            s16x8 bh = *(const s16x8*)(Whi + wo);
            acc[ct] = __builtin_amdgcn_mfma_f32_16x16x32_bf16(af, bl, acc[ct], 0, 0, 0);
            acc[ct] = __builtin_amdgcn_mfma_f32_16x16x32_bf16(af, bh, acc[ct], 0, 0, 0);
        }
    }
#pragma unroll
    for (int ct = 0; ct < 4; ++ct) {
        int col = col0 + ct * 16 + n16;
        float bv = bias[col];
        float s = 0.f, q = 0.f;
#pragma unroll
        for (int r = 0; r < 4; ++r) {
            float v = acc[ct][r] + bv;
            int row = m0 + quad * 4 + r;
            Y[(size_t)row * ldY + col] = f2b(v);
            s += v; q += v * v;
        }
        s += __shfl_xor(s, 16); q += __shfl_xor(q, 16);
        s += __shfl_xor(s, 32); q += __shfl_xor(q, 32);
        if (quad == 0) { red_s[wave][ct * 16 + n16] = s; red_q[wave][ct * 16 + n16] = q; }
    }
    if (stats) {
        __syncthreads();
        if (t < 64) {
            float s = red_s[0][t] + red_s[1][t] + red_s[2][t] + red_s[3][t];
            float q = red_q[0][t] + red_q[1][t] + red_q[2][t] + red_q[3][t];
            atomicAdd(&stats[col0 + t], s);
            atomicAdd(&stats[256 + col0 + t], q);
        }
    }
}

// ---------------- BN + ReLU (+ positional add), 8 elems/thread ----------------
__global__ __launch_bounds__(256) void bnrelu8_kernel(
    const bf16* __restrict__ Y, int N, const float* __restrict__ stats,
    const float* __restrict__ g, const float* __restrict__ beta,
    bf16* __restrict__ Out, const float* __restrict__ tab, const int* __restrict__ pos) {
    int i = (blockIdx.x * 256 + threadIdx.x) * 8;
    int col = i % N, row = i / N;
    uint4 raw = *(const uint4*)(Y + i);
    float v[8];
    v[0] = u2f(raw.x << 16); v[1] = u2f(raw.x & 0xffff0000u);
    v[2] = u2f(raw.y << 16); v[3] = u2f(raw.y & 0xffff0000u);
    v[4] = u2f(raw.z << 16); v[5] = u2f(raw.z & 0xffff0000u);
    v[6] = u2f(raw.w << 16); v[7] = u2f(raw.w & 0xffff0000u);
    const float invM = 1.f / (float)BT;
    const float* tr = tab ? (tab + pos[row] * 256 + col) : nullptr;
    bf16 tmp[8] __attribute__((aligned(16)));
#pragma unroll
    for (int j = 0; j < 8; ++j) {
        float mu  = stats[col + j] * invM;
        float var = stats[256 + col + j] * invM - mu * mu;
        float o = (v[j] - mu) * rsqrtf(var + 1e-5f) * g[col + j] + beta[col + j];
        o = fmaxf(o, 0.f);
        if (tr) o += tr[j];
        tmp[j] = f2b(o);
    }
    *(uint4*)(Out + i) = *(const uint4*)tmp;
}

// ---------------- pooled[b,f] += partial row-sum of a3 ----------------
__global__ __launch_bounds__(256) void pool_kernel(const bf16* __restrict__ a3,
                                                   float* __restrict__ pooled) {
    int b = blockIdx.x, part = blockIdx.y, f = threadIdx.x;
    int r0 = part * 46, r1 = min(r0 + 46, TT);
    const bf16* p = a3 + ((size_t)b * TT + r0) * 256 + f;
    float s = 0.f;
    for (int r = r0; r < r1; ++r, p += 256) s += b2f(*p);
    atomicAdd(&pooled[b * 256 + f], s);
}

// ---------------- SE MLP ----------------
__global__ __launch_bounds__(256) void se_mlp_kernel(const float* __restrict__ pooled,
                                                     const float* __restrict__ ws1,
                                                     const float* __restrict__ ws2,
                                                     float* __restrict__ se) {
    int b = blockIdx.x, f = threadIdx.x;
    __shared__ float pl[256];
    __shared__ float hidden[16];
    float p = pooled[b * 256 + f] * (1.f / (float)TT);
    pl[f] = p;
    __syncthreads();
    if (f < 16) {
        float h = 0.f;
        for (int k = 0; k < 256; ++k) h = fmaf(pl[k], ws1[f * 256 + k], h);
        hidden[f] = fmaxf(h, 0.f);
    }
    __syncthreads();
    float a = 0.f;
    for (int k = 0; k < 16; ++k) a = fmaf(hidden[k], ws2[f * 16 + k], a);
    a = 1.f / (1.f + expf(-a));
    se[b * 256 + f] = a * p;
}

// ---------------- residual ----------------
__global__ __launch_bounds__(256) void residual8_kernel(const bf16* __restrict__ a3,
                                                        const float* __restrict__ se,
                                                        bf16* __restrict__ out) {
    int i = (blockIdx.x * 256 + threadIdx.x) * 8;
    int col = i & 255, row = i >> 8;
    int b = row / TT;
    uint4 raw = *(const uint4*)(a3 + i);
    float v[8];
    v[0] = u2f(raw.x << 16); v[1] = u2f(raw.x & 0xffff0000u);
    v[2] = u2f(raw.y << 16); v[3] = u2f(raw.y & 0xffff0000u);
    v[4] = u2f(raw.z << 16); v[5] = u2f(raw.z & 0xffff0000u);
    v[6] = u2f(raw.w << 16); v[7] = u2f(raw.w & 0xffff0000u);
    const float* sp = se + b * 256 + col;
    bf16 tmp[8] __attribute__((aligned(16)));
#pragma unroll
    for (int j = 0; j < 8; ++j) tmp[j] = f2b(v[j] + sp[j]);
    *(uint4*)(out + i) = *(const uint4*)tmp;
}

// ---------------- fused attention: per b -> ksum, mean-score softmax, y ----------------
__global__ __launch_bounds__(256) void attn_kernel(
    const bf16* __restrict__ q, const bf16* __restrict__ k,
    const bf16* __restrict__ e, float* __restrict__ yv)
{
    __shared__ float sc[16][369];
    __shared__ float ks2[2][128];
    __shared__ float ksf[128];
    const int b = blockIdx.x, t = threadIdx.x;
    // phase 1: ksum over t
    {
        int f = t & 127, half = t >> 7;
        const bf16* base = k + ((size_t)b * TT + half) * 128 + f;
        float s = 0.f;
        for (int r = half; r < TT; r += 2, base += 256) s += b2f(*base);
        ks2[half][f] = s;
    }
    __syncthreads();
    if (t < 128) ksf[t] = ks2[0][t] + ks2[1][t];
    __syncthreads();
    // phase 2: scores[h][tt] = q . ksum / (sqrt(8)*T)
    {
        int h = t & 15, tt0 = t >> 4;
        float kk[8];
#pragma unroll
        for (int d = 0; d < 8; ++d) kk[d] = ksf[h * 8 + d];
        const float scale = 1.f / (sqrtf(8.f) * (float)TT);
        for (int c = 0; c < 23; ++c) {
            int tt = c * 16 + tt0;
            if (tt < TT) {
                uint4 raw = *(const uint4*)(q + ((size_t)b * TT + tt) * 128 + h * 8);
                float qv[8];
                qv[0] = u2f(raw.x << 16); qv[1] = u2f(raw.x & 0xffff0000u);
                qv[2] = u2f(raw.y << 16); qv[3] = u2f(raw.y & 0xffff0000u);
                qv[4] = u2f(raw.z << 16); qv[5] = u2f(raw.z & 0xffff0000u);
                qv[6] = u2f(raw.w << 16); qv[7] = u2f(raw.w & 0xffff0000u);
                float dot = 0.f;
#pragma unroll
                for (int d = 0; d < 8; ++d) dot = fmaf(qv[d], kk[d], dot);
                sc[h][tt] = dot * scale;
            }
        }
    }
    __syncthreads();
    // phase 3: softmax over tt per h (16 threads per h, lane-aligned groups)
    {
        int h = t >> 4, idx = t & 15;
        float m = -1e30f;
        for (int tt = idx; tt < TT; tt += 16) m = fmaxf(m, sc[h][tt]);
#pragma unroll
        for (int off = 1; off < 16; off <<= 1) m = fmaxf(m, __shfl_xor(m, off));
        float sum = 0.f;
        for (int tt = idx; tt < TT; tt += 16) { float ev = expf(sc[h][tt] - m); sc[h][tt] = ev; sum += ev; }
#pragma unroll
        for (int off = 1; off < 16; off <<= 1) sum += __shfl_xor(sum, off);
        float inv = 1.f / sum;
        for (int tt = idx; tt < TT; tt += 16) sc[h][tt] *= inv;
    }
    __syncthreads();
    // phase 4: yv[b,f] = sum_t a[h(f),t] * e[b,t,f]
    {
        int f = t, h = f >> 4;
        const bf16* base = e + (size_t)b * TT * 256 + f;
        float s = 0.f;
        for (int tt = 0; tt < TT; ++tt, base += 256) s = fmaf(sc[h][tt], b2f(*base), s);
        yv[b * 256 + f] = s;
    }
}

// ---------------- fused tail: 1024 threads, wave = 64 rows of one col-group ----------------
// LDS (dwords): Xq@0 [64k][65r]=4160 ; Z1t@4160 [128c][65r]=8320 ; Z2t@0 [64c][65r]=4160 ;
//               Z3t@12480 [32c][65r]=2080 ; total 14560 dwords = 58240 B
__global__ __launch_bounds__(1024) void tail_kernel(
    const float* __restrict__ yv,
    const float* wm, const float* bm, const float* gm, const float* em,
    const float* wd1, const float* bd1, const float* gd1, const float* ed1,
    const float* wd2, const float* bd2, const float* gd2, const float* ed2,
    const float* wc, const float* bc, float* __restrict__ out)
{
    __shared__ float lds[14560];
    float* Xq  = lds;
    float* Z1t = lds + 4160;
    float* Z2t = lds;
    float* Z3t = lds + 12480;
    const int t = threadIdx.x;
    const int r = t & 63, cg = t >> 6;

    // ---- layer 1: 256 -> 128, X staged in 4 quarters ----
    float acc1[8];
#pragma unroll
    for (int c = 0; c < 8; ++c) acc1[c] = 0.f;
    const int c01 = cg * 8;
    for (int p = 0; p < 4; ++p) {
        __syncthreads();
        for (int i = t; i < 4096; i += 1024) {
            int rr = i >> 6, kk = i & 63;
            Xq[kk * 65 + rr] = yv[rr * 256 + p * 64 + kk];
        }
        __syncthreads();
#pragma unroll 4
        for (int k4 = 0; k4 < 16; ++k4) {
            float xv[4];
#pragma unroll
            for (int j = 0; j < 4; ++j) xv[j] = Xq[(k4 * 4 + j) * 65 + r];
#pragma unroll
            for (int c = 0; c < 8; ++c) {
                const float4 w = *(const float4*)(wm + (size_t)(c01 + c) * 256 + p * 64 + k4 * 4);
                acc1[c] = fmaf(xv[0], w.x, acc1[c]);
                acc1[c] = fmaf(xv[1], w.y, acc1[c]);
                acc1[c] = fmaf(xv[2], w.z, acc1[c]);
                acc1[c] = fmaf(xv[3], w.w, acc1[c]);
            }
        }
    }
#pragma unroll
    for (int c = 0; c < 8; ++c) {
        float v = acc1[c] + bm[c01 + c];
        float s = v, q = v * v;
#pragma unroll
        for (int off = 1; off < 64; off <<= 1) { s += __shfl_xor(s, off); q += __shfl_xor(q, off); }
        float mu = s * (1.f / 64.f), var = q * (1.f / 64.f) - mu * mu;
        float z = fmaxf((v - mu) * rsqrtf(var + 1e-5f) * gm[c01 + c] + em[c01 + c], 0.f);
        Z1t[(c01 + c) * 65 + r] = z;
    }
    __syncthreads();
    // ---- layer 2: 128 -> 64 ----
    float acc2[4] = {0.f, 0.f, 0.f, 0.f};
    const int c02 = cg * 4;
#pragma unroll 4
    for (int k4 = 0; k4 < 32; ++k4) {
        float xv[4];
#pragma unroll
        for (int j = 0; j < 4; ++j) xv[j] = Z1t[(k4 * 4 + j) * 65 + r];
#pragma unroll
        for (int c = 0; c < 4; ++c) {
            const float4 w = *(const float4*)(wd1 + (size_t)(c02 + c) * 128 + k4 * 4);
            acc2[c] = fmaf(xv[0], w.x, acc2[c]);
            acc2[c] = fmaf(xv[1], w.y, acc2[c]);
            acc2[c] = fmaf(xv[2], w.z, acc2[c]);
            acc2[c] = fmaf(xv[3], w.w, acc2[c]);
        }
    }
    float z2v[4];
#pragma unroll
    for (int c = 0; c < 4; ++c) {
        float v = acc2[c] + bd1[c02 + c];
        float s = v, q = v * v;
#pragma unroll
        for (int off = 1; off < 64; off <<= 1) { s += __shfl_xor(s, off); q += __shfl_xor(q, off); }
        float mu = s * (1.f / 64.f), var = q * (1.f / 64.f) - mu * mu;
        z2v[c] = fmaxf((v - mu) * rsqrtf(var + 1e-5f) * gd1[c02 + c] + ed1[c02 + c], 0.f);
    }
    __syncthreads();   // Z1t reads done; Z2t aliases Xq (dead)
#pragma unroll
    for (int c = 0; c < 4; ++c) Z2t[(c02 + c) * 65 + r] = z2v[c];
    __syncthreads();
    // ---- layer 3: 64 -> 32 ----
    float acc3[2] = {0.f, 0.f};
    const int c03 = cg * 2;
#pragma unroll 4
    for (int k4 = 0; k4 < 16; ++k4) {
        float xv[4];
#pragma unroll
        for (int j = 0; j < 4; ++j) xv[j] = Z2t[(k4 * 4 + j) * 65 + r];
#pragma unroll
        for (int c = 0; c < 2; ++c) {
            const float4 w = *(const float4*)(wd2 + (size_t)(c03 + c) * 64 + k4 * 4);
            acc3[c] = fmaf(xv[0], w.x, acc3[c]);
            acc3[c] = fmaf(xv[1], w.y, acc3[c]);
            acc3[c] = fmaf(xv[2], w.z, acc3[c]);
            acc3[c] = fmaf(xv[3], w.w, acc3[c]);
        }
    }
#pragma unroll
    for (int c = 0; c < 2; ++c) {
        float v = acc3[c] + bd2[c03 + c];
        float s = v, q = v * v;
#pragma unroll
        for (int off = 1; off < 64; off <<= 1) { s += __shfl_xor(s, off); q += __shfl_xor(q, off); }
        float mu = s * (1.f / 64.f), var = q * (1.f / 64.f) - mu * mu;
        Z3t[(c03 + c) * 65 + r] = fmaxf((v - mu) * rsqrtf(var + 1e-5f) * gd2[c03 + c] + ed2[c03 + c], 0.f);
    }
    __syncthreads();
    // ---- classifier: [64,32] @ wc^T + bc -> out[64,10] ----
    if (t < 640) {
        int rr = t / 10, c = t % 10;
        float s = bc[c];
#pragma unroll
        for (int kk = 0; kk < 32; ++kk) s = fmaf(Z3t[kk * 65 + rr], wc[c * 32 + kk], s);
        out[t] = s;
    }
}

// ---------------- launch ----------------

extern "C" void kernel_launch(void* const* d_in, const int* in_sizes, int n_in,
                              void* d_out, int out_size, void* d_ws, size_t ws_size,
                              hipStream_t stream) {
    (void)in_sizes; (void)n_in; (void)out_size; (void)ws_size;
    const float* x  = (const float*)d_in[0];
    const int* pos  = (const int*)d_in[1];
    const float *w1 = (const float*)d_in[2],  *b1 = (const float*)d_in[3],
                *g1 = (const float*)d_in[4],  *e1 = (const float*)d_in[5];
    const float *w2 = (const float*)d_in[6],  *b2 = (const float*)d_in[7],
                *g2 = (const float*)d_in[8],  *e2 = (const float*)d_in[9];
    const float *w3 = (const float*)d_in[10], *b3 = (const float*)d_in[11],
                *g3 = (const float*)d_in[12], *e3 = (const float*)d_in[13];
    const float *ws1 = (const float*)d_in[14], *ws2 = (const float*)d_in[15];
    const float *wi = (const float*)d_in[16], *bi = (const float*)d_in[17],
                *gi = (const float*)d_in[18], *ei = (const float*)d_in[19];
    const float *wk = (const float*)d_in[20], *bk = (const float*)d_in[21];   // k before q!
    const float *wq = (const float*)d_in[22], *bq = (const float*)d_in[23];
    const float *wm = (const float*)d_in[24], *bm = (const float*)d_in[25],
                *gm = (const float*)d_in[26], *em = (const float*)d_in[27];
    const float *wd1 = (const float*)d_in[28], *bd1 = (const float*)d_in[29],
                *gd1 = (const float*)d_in[30], *ed1 = (const float*)d_in[31];
    const float *wd2 = (const float*)d_in[32], *bd2 = (const float*)d_in[33],
                *gd2 = (const float*)d_in[34], *ed2 = (const float*)d_in[35];
    const float *wc = (const float*)d_in[36], *bc = (const float*)d_in[37];
    float* out = (float*)d_out;

    // workspace layout (bytes), total ~25.7 MB, all 16B-aligned
    char* w8 = (char*)d_ws;
    bf16*  actA   = (bf16*)(w8);                    // 11,960,320
    bf16*  actB   = (bf16*)(w8 + 11960320);         // 11,960,320
    bf16*  xb     = (bf16*)(w8 + 23920640);         //    467,200
    bf16*  whi    = (bf16*)(w8 + 24387840);         //    344,064
    bf16*  wlo    = (bf16*)(w8 + 24731904);         //    344,064
    float* tab    = (float*)(w8 + 25075968);        //    435,200
    float* stats  = (float*)(w8 + 25511168);        //      8,192
    float* pooled = (float*)(w8 + 25519360);        //     65,536
    float* sebuf  = (float*)(w8 + 25584896);        //     65,536
    float* yvb    = (float*)(w8 + 25650432);        //     65,536
    bf16*  qbuf   = actA;
    bf16*  kbuf   = actA + (size_t)BT * 128;

    prep_kernel<<<2082, 256, 0, stream>>>(stats, pooled, x, xb,
                                          w2, w3, wi, wq, wk, whi, wlo, tab);
    // encoder L1: 10 -> 64
    gemm_l1_kernel<<<365, 256, 0, stream>>>(xb, w1, b1, actB, stats);
    bnrelu8_kernel<<<BT * 64 / 2048, 256, 0, stream>>>(actB, 64, stats, g1, e1, actA, nullptr, nullptr);
    // encoder L2: 64 -> 128 (MFMA)
    mfma_gemm<<<dim3(365, 2), 256, 0, stream>>>(actA, 64, whi, wlo, b2, actB, 128, stats + 512);
    bnrelu8_kernel<<<BT * 128 / 2048, 256, 0, stream>>>(actB, 128, stats + 512, g2, e2, actA, nullptr, nullptr);
    // encoder L3: 128 -> 256 (MFMA)
    mfma_gemm<<<dim3(365, 4), 256, 0, stream>>>(actA, 128, whi + 8192, wlo + 8192, b3, actB, 256, stats + 1024);
    bnrelu8_kernel<<<BT * 256 / 2048, 256, 0, stream>>>(actB, 256, stats + 1024, g3, e3, actA, nullptr, nullptr);
    // SE + residual
    pool_kernel<<<dim3(64, 8), 256, 0, stream>>>(actA, pooled);
    se_mlp_kernel<<<64, 256, 0, stream>>>(pooled, ws1, ws2, sebuf);
    residual8_kernel<<<BT * 256 / 2048, 256, 0, stream>>>(actA, sebuf, actB);
    // inconv 256 -> 256 (MFMA), BN/ReLU + positional add -> e (actB)
    mfma_gemm<<<dim3(365, 4), 256, 0, stream>>>(actB, 256, whi + 40960, wlo + 40960, bi, actA, 256, stats + 1536);
    bnrelu8_kernel<<<BT * 256 / 2048, 256, 0, stream>>>(actA, 256, stats + 1536, gi, ei, actB, tab, pos);
    // q,k projections (MFMA)
    mfma_gemm<<<dim3(365, 2), 256, 0, stream>>>(actB, 256, whi + 106496, wlo + 106496, bq, qbuf, 128, nullptr);
    mfma_gemm<<<dim3(365, 2), 256, 0, stream>>>(actB, 256, whi + 139264, wlo + 139264, bk, kbuf, 128, nullptr);
    // fused attention
    attn_kernel<<<64, 256, 0, stream>>>(qbuf, kbuf, actB, yvb);
    // fused tail
    tail_kernel<<<1, 1024, 0, stream>>>(yvb, wm, bm, gm, em, wd1, bd1, gd1, ed1,
                                        wd2, bd2, gd2, ed2, wc, bc, out);
}

// Round 6
// 491.390 us; speedup vs baseline: 1.3018x; 1.3018x over previous
//
#include <hip/hip_runtime.h>
#include <hip/hip_bf16.h>
#include <math.h>

#define TT 365
#define BT 23360
#define NPOS 425

typedef __hip_bfloat16 bf16;
typedef __attribute__((ext_vector_type(8))) short s16x8;
typedef __attribute__((ext_vector_type(4))) float f32x4;

__device__ __forceinline__ float b2f(bf16 v) { return __bfloat162float(v); }
__device__ __forceinline__ bf16  f2b(float v) { return __float2bfloat16(v); }
__device__ __forceinline__ float u2f(unsigned u) { return __uint_as_float(u); }
__device__ __forceinline__ short f2bs(float v) { bf16 h = __float2bfloat16(v); return *reinterpret_cast<short*>(&h); }

// ---------------- prep: zero stats, split-cast weights, pos table, concat q/k bias ----------------
// whi/wlo element offsets: w2@0(8192) w3@8192(32768) wi@40960(65536) wq@106496(32768) wk@139264(32768)
__global__ __launch_bounds__(256) void prep_kernel(
    float* __restrict__ stats,
    const float* __restrict__ w2, const float* __restrict__ w3, const float* __restrict__ wi,
    const float* __restrict__ wq, const float* __restrict__ wk,
    bf16* __restrict__ whi, bf16* __restrict__ wlo, float* __restrict__ tab,
    const float* __restrict__ bq, const float* __restrict__ bk, float* __restrict__ bqk)
{
    int i = blockIdx.x * 256 + threadIdx.x;
    if (i < 2048) { stats[i] = 0.f; return; } i -= 2048;
    if (i < 172032) {
        float w;
        if      (i < 8192)   w = w2[i];
        else if (i < 40960)  w = w3[i - 8192];
        else if (i < 106496) w = wi[i - 40960];
        else if (i < 139264) w = wq[i - 106496];
        else                 w = wk[i - 139264];
        bf16 h = f2b(w);
        whi[i] = h;
        wlo[i] = f2b(w - b2f(h));
        return;
    } i -= 172032;
    if (i < 108800) {
        int c = i & 255, p = i >> 8;
        float e = (float)(2 * (c >> 1)) * (1.f / 256.f);
        float ang = (float)p * exp2f(-e * 9.96578428466209f);   // 1000^-e
        tab[i] = (c & 1) ? cosf(ang) : sinf(ang);
        return;
    } i -= 108800;
    if (i < 256) bqk[i] = (i < 128) ? bq[i] : bk[i - 128];
}

// ---------------- L1 GEMM (K=10, f32 A): Y[M,64](bf16) = x @ w1^T + b1; fused BN stats ----------
__global__ __launch_bounds__(256) void gemm_l1_kernel(
    const float* __restrict__ x,
    const float* __restrict__ W, const float* __restrict__ bias,
    bf16* __restrict__ Y, float* __restrict__ stats)
{
    const int t  = threadIdx.x;
    const int tx = t & 15, ty = t >> 4;
    const int row0 = blockIdx.x * 64;
    __shared__ float As[64][17];
    __shared__ float Ws[16][65];
    __shared__ float red_s[4][64];
    __shared__ float red_q[4][64];
    float acc[4][4];
#pragma unroll
    for (int rr = 0; rr < 4; ++rr)
#pragma unroll
        for (int cc = 0; cc < 4; ++cc) acc[rr][cc] = 0.f;
#pragma unroll
    for (int i = 0; i < 4; ++i) {
        int idx = t + i * 256, r = idx >> 4, c = idx & 15;
        As[r][c] = (c < 10) ? x[(size_t)(row0 + r) * 10 + c] : 0.f;
    }
#pragma unroll
    for (int i = 0; i < 4; ++i) {
        int idx = t + i * 256, c = idx >> 4, kk = idx & 15;
        Ws[kk][c] = (kk < 10) ? W[(size_t)c * 10 + kk] : 0.f;
    }
    __syncthreads();
#pragma unroll
    for (int kk = 0; kk < 10; ++kk) {
        float a[4];
#pragma unroll
        for (int rr = 0; rr < 4; ++rr) a[rr] = As[ty * 4 + rr][kk];
#pragma unroll
        for (int cc = 0; cc < 4; ++cc) {
            float w = Ws[kk][cc * 16 + tx];
#pragma unroll
            for (int rr = 0; rr < 4; ++rr) acc[rr][cc] = fmaf(a[rr], w, acc[rr][cc]);
        }
    }
    float s_cc[4], q_cc[4];
#pragma unroll
    for (int cc = 0; cc < 4; ++cc) { s_cc[cc] = 0.f; q_cc[cc] = 0.f; }
#pragma unroll
    for (int rr = 0; rr < 4; ++rr) {
        int row = row0 + ty * 4 + rr;
#pragma unroll
        for (int cc = 0; cc < 4; ++cc) {
            int col = cc * 16 + tx;
            float v = acc[rr][cc] + bias[col];
            Y[(size_t)row * 64 + col] = f2b(v);
            s_cc[cc] += v; q_cc[cc] += v * v;
        }
    }
    int w = t >> 6;
#pragma unroll
    for (int cc = 0; cc < 4; ++cc) {
        float s = s_cc[cc], q = q_cc[cc];
        s += __shfl_xor(s, 16); q += __shfl_xor(q, 16);
        s += __shfl_xor(s, 32); q += __shfl_xor(q, 32);
        if ((t & 63) < 16) { red_s[w][cc * 16 + tx] = s; red_q[w][cc * 16 + tx] = q; }
    }
    __syncthreads();
    if (t < 64) {
        float s = red_s[0][t] + red_s[1][t] + red_s[2][t] + red_s[3][t];
        float q = red_q[0][t] + red_q[1][t] + red_q[2][t] + red_q[3][t];
        atomicAdd(&stats[t], s);
        atomicAdd(&stats[256 + t], q);
    }
}

// ---------------- MFMA GEMM, optional fused BN+ReLU on the A operand ----------------
// 64 rows x 64 cols per block (4 waves x 16 rows). A-frag A[m=lane&15][k=quad*8+j];
// C: col=lane&15, row=quad*4+r. FUSED: A is raw pre-BN; apply y*sc[k]+sh[k], relu, f2b.
template<bool FUSED>
__global__ __launch_bounds__(256) void mfma_gemm(
    const bf16* __restrict__ A, int K,
    const bf16* __restrict__ Whi, const bf16* __restrict__ Wlo,
    const float* __restrict__ bias,
    bf16* __restrict__ Y, int ldY, float* __restrict__ stats,
    const float* __restrict__ bnstats, const float* __restrict__ bng,
    const float* __restrict__ bnb)
{
    __shared__ float red_s[4][64];
    __shared__ float red_q[4][64];
    __shared__ float scb[FUSED ? 256 : 1];
    __shared__ float shb[FUSED ? 256 : 1];
    const int t = threadIdx.x, wave = t >> 6, lane = t & 63;
    const int n16 = lane & 15, quad = lane >> 4;
    const int m0 = blockIdx.x * 64 + wave * 16;
    const int col0 = blockIdx.y * 64;
    if (FUSED) {
        if (t < K) {
            float mu = bnstats[t] * (1.f / (float)BT);
            float var = bnstats[256 + t] * (1.f / (float)BT) - mu * mu;
            float sc = rsqrtf(var + 1e-5f) * bng[t];
            scb[t] = sc; shb[t] = bnb[t] - mu * sc;
        }
        __syncthreads();
    }
    f32x4 acc[4];
    f32x4 zero = {0.f, 0.f, 0.f, 0.f};
#pragma unroll
    for (int ct = 0; ct < 4; ++ct) acc[ct] = zero;
    const bf16* Ap = A + (size_t)(m0 + n16) * K + quad * 8;
    const size_t wbase = (size_t)(col0 + n16) * K + quad * 8;
#pragma unroll 2
    for (int k0 = 0; k0 < K; k0 += 32) {
        s16x8 af;
        if (FUSED) {
            s16x8 raw = *(const s16x8*)(Ap + k0);
            int kb = k0 + quad * 8;
#pragma unroll
            for (int j = 0; j < 8; ++j) {
                float y = u2f(((unsigned)(unsigned short)raw[j]) << 16);
                af[j] = f2bs(fmaxf(fmaf(y, scb[kb + j], shb[kb + j]), 0.f));
            }
        } else {
            af = *(const s16x8*)(Ap + k0);
        }
#pragma unroll
        for (int ct = 0; ct < 4; ++ct) {
            size_t wo = wbase + (size_t)ct * 16 * K + k0;
            s16x8 bl = *(const s16x8*)(Wlo + wo);
            s16x8 bh = *(const s16x8*)(Whi + wo);
            acc[ct] = __builtin_amdgcn_mfma_f32_16x16x32_bf16(af, bl, acc[ct], 0, 0, 0);
            acc[ct] = __builtin_amdgcn_mfma_f32_16x16x32_bf16(af, bh, acc[ct], 0, 0, 0);
        }
    }
#pragma unroll
    for (int ct = 0; ct < 4; ++ct) {
        int col = col0 + ct * 16 + n16;
        float bv = bias[col];
        float s = 0.f, q = 0.f;
#pragma unroll
        for (int r = 0; r < 4; ++r) {
            float v = acc[ct][r] + bv;
            int row = m0 + quad * 4 + r;
            Y[(size_t)row * ldY + col] = f2b(v);
            s += v; q += v * v;
        }
        s += __shfl_xor(s, 16); q += __shfl_xor(q, 16);
        s += __shfl_xor(s, 32); q += __shfl_xor(q, 32);
        if (quad == 0) { red_s[wave][ct * 16 + n16] = s; red_q[wave][ct * 16 + n16] = q; }
    }
    if (stats) {
        __syncthreads();
        if (t < 64) {
            float s = red_s[0][t] + red_s[1][t] + red_s[2][t] + red_s[3][t];
            float q = red_q[0][t] + red_q[1][t] + red_q[2][t] + red_q[3][t];
            atomicAdd(&stats[col0 + t], s);
            atomicAdd(&stats[256 + col0 + t], q);
        }
    }
}

// ---------------- fused bn3+relu + pool + SE-MLP + residual: rout = a3 + se[b,:] ----------------
__global__ __launch_bounds__(256) void bnpoolse_kernel(
    const bf16* __restrict__ Y3, const float* __restrict__ stats,
    const float* __restrict__ g3, const float* __restrict__ e3,
    const float* __restrict__ ws1, const float* __restrict__ ws2,
    bf16* __restrict__ rout)
{
    const int b = blockIdx.x, f = threadIdx.x;
    __shared__ float pl[256], hidden[16];
    float mu = stats[f] * (1.f / (float)BT);
    float var = stats[256 + f] * (1.f / (float)BT) - mu * mu;
    float sc = rsqrtf(var + 1e-5f) * g3[f];
    float sh = e3[f] - mu * sc;
    const bf16* yp = Y3 + (size_t)b * TT * 256 + f;
    float s = 0.f;
    for (int tt = 0; tt < TT; ++tt)
        s += fmaxf(fmaf(b2f(yp[(size_t)tt * 256]), sc, sh), 0.f);
    float p = s * (1.f / (float)TT);
    pl[f] = p;
    __syncthreads();
    if (f < 16) {
        float h = 0.f;
        for (int k2 = 0; k2 < 256; ++k2) h = fmaf(pl[k2], ws1[f * 256 + k2], h);
        hidden[f] = fmaxf(h, 0.f);
    }
    __syncthreads();
    float a = 0.f;
    for (int k2 = 0; k2 < 16; ++k2) a = fmaf(hidden[k2], ws2[f * 16 + k2], a);
    a = 1.f / (1.f + expf(-a));
    float sev = a * p;
    bf16* op = rout + (size_t)b * TT * 256 + f;
    for (int tt = 0; tt < TT; ++tt)
        op[(size_t)tt * 256] = f2b(fmaxf(fmaf(b2f(yp[(size_t)tt * 256]), sc, sh), 0.f) + sev);
}

// ---------------- BN + ReLU + positional add (inconv output -> e), 8 elems/thread ----------------
__global__ __launch_bounds__(256) void bnrelu8_kernel(
    const bf16* __restrict__ Y, const float* __restrict__ stats,
    const float* __restrict__ g, const float* __restrict__ beta,
    bf16* __restrict__ Out, const float* __restrict__ tab, const int* __restrict__ pos) {
    int i = (blockIdx.x * 256 + threadIdx.x) * 8;
    int col = i & 255, row = i >> 8;
    uint4 raw = *(const uint4*)(Y + i);
    float v[8];
    v[0] = u2f(raw.x << 16); v[1] = u2f(raw.x & 0xffff0000u);
    v[2] = u2f(raw.y << 16); v[3] = u2f(raw.y & 0xffff0000u);
    v[4] = u2f(raw.z << 16); v[5] = u2f(raw.z & 0xffff0000u);
    v[6] = u2f(raw.w << 16); v[7] = u2f(raw.w & 0xffff0000u);
    const float invM = 1.f / (float)BT;
    const float* tr = tab + pos[row] * 256 + col;
    bf16 tmp[8] __attribute__((aligned(16)));
#pragma unroll
    for (int j = 0; j < 8; ++j) {
        float mu  = stats[col + j] * invM;
        float var = stats[256 + col + j] * invM - mu * mu;
        float o = (v[j] - mu) * rsqrtf(var + 1e-5f) * g[col + j] + beta[col + j];
        tmp[j] = f2b(fmaxf(o, 0.f) + tr[j]);
    }
    *(uint4*)(Out + i) = *(const uint4*)tmp;
}

// ---------------- fused attention on combined qk buffer [BT,256]: q=[:,0:128], k=[:,128:256] ----
__global__ __launch_bounds__(256) void attn_kernel(
    const bf16* __restrict__ qk, const bf16* __restrict__ e, float* __restrict__ yv)
{
    __shared__ float sc[16][369];
    __shared__ float ks2[2][128];
    __shared__ float ksf[128];
    const int b = blockIdx.x, t = threadIdx.x;
    {   // ksum over t
        int f = t & 127, half = t >> 7;
        const bf16* base = qk + ((size_t)b * TT + half) * 256 + 128 + f;
        float s = 0.f;
        for (int r = half; r < TT; r += 2, base += 512) s += b2f(*base);
        ks2[half][f] = s;
    }
    __syncthreads();
    if (t < 128) ksf[t] = ks2[0][t] + ks2[1][t];
    __syncthreads();
    {   // scores
        int h = t & 15, tt0 = t >> 4;
        float kk[8];
#pragma unroll
        for (int d = 0; d < 8; ++d) kk[d] = ksf[h * 8 + d];
        const float scale = 1.f / (sqrtf(8.f) * (float)TT);
        for (int c = 0; c < 23; ++c) {
            int tt = c * 16 + tt0;
            if (tt < TT) {
                uint4 raw = *(const uint4*)(qk + ((size_t)b * TT + tt) * 256 + h * 8);
                float qv[8];
                qv[0] = u2f(raw.x << 16); qv[1] = u2f(raw.x & 0xffff0000u);
                qv[2] = u2f(raw.y << 16); qv[3] = u2f(raw.y & 0xffff0000u);
                qv[4] = u2f(raw.z << 16); qv[5] = u2f(raw.z & 0xffff0000u);
                qv[6] = u2f(raw.w << 16); qv[7] = u2f(raw.w & 0xffff0000u);
                float dot = 0.f;
#pragma unroll
                for (int d = 0; d < 8; ++d) dot = fmaf(qv[d], kk[d], dot);
                sc[h][tt] = dot * scale;
            }
        }
    }
    __syncthreads();
    {   // softmax per h
        int h = t >> 4, idx = t & 15;
        float m = -1e30f;
        for (int tt = idx; tt < TT; tt += 16) m = fmaxf(m, sc[h][tt]);
#pragma unroll
        for (int off = 1; off < 16; off <<= 1) m = fmaxf(m, __shfl_xor(m, off));
        float sum = 0.f;
        for (int tt = idx; tt < TT; tt += 16) { float ev = expf(sc[h][tt] - m); sc[h][tt] = ev; sum += ev; }
#pragma unroll
        for (int off = 1; off < 16; off <<= 1) sum += __shfl_xor(sum, off);
        float inv = 1.f / sum;
        for (int tt = idx; tt < TT; tt += 16) sc[h][tt] *= inv;
    }
    __syncthreads();
    {   // yv
        int f = t, h = f >> 4;
        const bf16* base = e + (size_t)b * TT * 256 + f;
        float s = 0.f;
        for (int tt = 0; tt < TT; ++tt, base += 256) s = fmaf(sc[h][tt], b2f(*base), s);
        yv[b * 256 + f] = s;
    }
}

// ---------------- fused tail, 1024 threads, ALL weights staged in LDS ----------------
// LDS floats: L1: Xq@0 [64k][65] (4160) + Wp@4160 [128c][64k] (8192) -> 12352
//             L2: Z1t@0 [128c][64r] (8192) + Wd1h@8192 [64c][64k] (4096)
//             L3: Z2t@0 (4096) + Wd2@4096 (2048) + Z3t@6144 (2048) + WcL@8192 (320)
__global__ __launch_bounds__(1024) void tail_kernel(
    const float* __restrict__ yv,
    const float* wm, const float* bm, const float* gm, const float* em,
    const float* wd1, const float* bd1, const float* gd1, const float* ed1,
    const float* wd2, const float* bd2, const float* gd2, const float* ed2,
    const float* wc, const float* bc, float* __restrict__ out)
{
    __shared__ float lds[12352];
    const int t = threadIdx.x;
    const int r = t & 63, cg = t >> 6;
    float* Xq  = lds;            // [64k][65]
    float* Wp  = lds + 4160;     // [128c][64k]
    float* Z1t = lds;            // [128c][64r]
    float* Wd1h = lds + 8192;    // [64c][64k]
    float* Z2t = lds;            // [64c][64r]
    float* Wd2 = lds + 4096;     // [32c][64k]
    float* Z3t = lds + 6144;     // [32c][64r]
    float* WcL = lds + 8192;     // [10c][32k]

    // ---- layer 1: 256 -> 128, K in 4 chunks of 64 ----
    float acc1[8] = {0.f,0.f,0.f,0.f,0.f,0.f,0.f,0.f};
    const int c01 = cg * 8;
    for (int p = 0; p < 4; ++p) {
        __syncthreads();
        for (int i = t; i < 4096; i += 1024) {
            int kk = i & 63, rr = i >> 6;
            Xq[kk * 65 + rr] = yv[rr * 256 + p * 64 + kk];    // coalesced read, conflict-free write
        }
        {
            const float4* wm4 = (const float4*)wm;            // row = 64 float4
            float4* Wp4 = (float4*)Wp;
            for (int i = t; i < 2048; i += 1024) {
                int kk4 = i & 15, c = i >> 4;
                Wp4[c * 16 + kk4] = wm4[c * 64 + p * 16 + kk4];
            }
        }
        __syncthreads();
#pragma unroll 4
        for (int k4 = 0; k4 < 16; ++k4) {
            float xv[4];
#pragma unroll
            for (int j = 0; j < 4; ++j) xv[j] = Xq[(k4 * 4 + j) * 65 + r];
#pragma unroll
            for (int c = 0; c < 8; ++c) {
                float4 w = *(const float4*)(Wp + (c01 + c) * 64 + k4 * 4);
                acc1[c] = fmaf(xv[0], w.x, acc1[c]);
                acc1[c] = fmaf(xv[1], w.y, acc1[c]);
                acc1[c] = fmaf(xv[2], w.z, acc1[c]);
                acc1[c] = fmaf(xv[3], w.w, acc1[c]);
            }
        }
    }
    float z1v[8];
#pragma unroll
    for (int c = 0; c < 8; ++c) {
        float v = acc1[c] + bm[c01 + c];
        float s = v, q = v * v;
#pragma unroll
        for (int off = 1; off < 64; off <<= 1) { s += __shfl_xor(s, off); q += __shfl_xor(q, off); }
        float mu = s * (1.f / 64.f), var = q * (1.f / 64.f) - mu * mu;
        z1v[c] = fmaxf((v - mu) * rsqrtf(var + 1e-5f) * gm[c01 + c] + em[c01 + c], 0.f);
    }
    __syncthreads();
#pragma unroll
    for (int c = 0; c < 8; ++c) Z1t[(c01 + c) * 64 + r] = z1v[c];
    // ---- layer 2: 128 -> 64, K in 2 chunks of 64 ----
    float acc2[4] = {0.f, 0.f, 0.f, 0.f};
    const int c02 = cg * 4;
    for (int ph = 0; ph < 2; ++ph) {
        __syncthreads();
        {
            const float4* s4 = (const float4*)wd1;            // row = 32 float4
            float4* d4 = (float4*)Wd1h;
            if (t < 1024) {
                int kk4 = t & 15, c = t >> 4;
                d4[c * 16 + kk4] = s4[c * 32 + ph * 16 + kk4];
            }
        }
        __syncthreads();
#pragma unroll 4
        for (int k4 = 0; k4 < 16; ++k4) {
            float xv[4];
#pragma unroll
            for (int j = 0; j < 4; ++j) xv[j] = Z1t[(ph * 64 + k4 * 4 + j) * 64 + r];
#pragma unroll
            for (int c = 0; c < 4; ++c) {
                float4 w = *(const float4*)(Wd1h + (c02 + c) * 64 + k4 * 4);
                acc2[c] = fmaf(xv[0], w.x, acc2[c]);
                acc2[c] = fmaf(xv[1], w.y, acc2[c]);
                acc2[c] = fmaf(xv[2], w.z, acc2[c]);
                acc2[c] = fmaf(xv[3], w.w, acc2[c]);
            }
        }
    }
    float z2v[4];
#pragma unroll
    for (int c = 0; c < 4; ++c) {
        float v = acc2[c] + bd1[c02 + c];
        float s = v, q = v * v;
#pragma unroll
        for (int off = 1; off < 64; off <<= 1) { s += __shfl_xor(s, off); q += __shfl_xor(q, off); }
        float mu = s * (1.f / 64.f), var = q * (1.f / 64.f) - mu * mu;
        z2v[c] = fmaxf((v - mu) * rsqrtf(var + 1e-5f) * gd1[c02 + c] + ed1[c02 + c], 0.f);
    }
    __syncthreads();
#pragma unroll
    for (int c = 0; c < 4; ++c) Z2t[(c02 + c) * 64 + r] = z2v[c];
    {   // stage wd2 [32][64] = 512 float4
        const float4* s4 = (const float4*)wd2;
        float4* d4 = (float4*)Wd2;
        if (t < 512) d4[t] = s4[t];
    }
    __syncthreads();
    // ---- layer 3: 64 -> 32 ----
    float acc3[2] = {0.f, 0.f};
    const int c03 = cg * 2;
#pragma unroll 4
    for (int k4 = 0; k4 < 16; ++k4) {
        float xv[4];
#pragma unroll
        for (int j = 0; j < 4; ++j) xv[j] = Z2t[(k4 * 4 + j) * 64 + r];
#pragma unroll
        for (int c = 0; c < 2; ++c) {
            float4 w = *(const float4*)(Wd2 + (c03 + c) * 64 + k4 * 4);
            acc3[c] = fmaf(xv[0], w.x, acc3[c]);
            acc3[c] = fmaf(xv[1], w.y, acc3[c]);
            acc3[c] = fmaf(xv[2], w.z, acc3[c]);
            acc3[c] = fmaf(xv[3], w.w, acc3[c]);
        }
    }
#pragma unroll
    for (int c = 0; c < 2; ++c) {
        float v = acc3[c] + bd2[c03 + c];
        float s = v, q = v * v;
#pragma unroll
        for (int off = 1; off < 64; off <<= 1) { s += __shfl_xor(s, off); q += __shfl_xor(q, off); }
        float mu = s * (1.f / 64.f), var = q * (1.f / 64.f) - mu * mu;
        Z3t[(c03 + c) * 64 + r] = fmaxf((v - mu) * rsqrtf(var + 1e-5f) * gd2[c03 + c] + ed2[c03 + c], 0.f);
    }
    if (t < 80) ((float4*)WcL)[t] = ((const float4*)wc)[t];   // wc [10][32] = 80 float4
    __syncthreads();
    // ---- classifier ----
    if (t < 640) {
        int rr = t / 10, c = t % 10;
        float s = bc[c];
#pragma unroll
        for (int kk = 0; kk < 32; ++kk) s = fmaf(Z3t[kk * 64 + rr], WcL[c * 32 + kk], s);
        out[t] = s;
    }
}

// ---------------- launch ----------------

extern "C" void kernel_launch(void* const* d_in, const int* in_sizes, int n_in,
                              void* d_out, int out_size, void* d_ws, size_t ws_size,
                              hipStream_t stream) {
    (void)in_sizes; (void)n_in; (void)out_size; (void)ws_size;
    const float* x  = (const float*)d_in[0];
    const int* pos  = (const int*)d_in[1];
    const float *w1 = (const float*)d_in[2],  *b1 = (const float*)d_in[3],
                *g1 = (const float*)d_in[4],  *e1 = (const float*)d_in[5];
    const float *w2 = (const float*)d_in[6],  *b2 = (const float*)d_in[7],
                *g2 = (const float*)d_in[8],  *e2 = (const float*)d_in[9];
    const float *w3 = (const float*)d_in[10], *b3 = (const float*)d_in[11],
                *g3 = (const float*)d_in[12], *e3 = (const float*)d_in[13];
    const float *ws1 = (const float*)d_in[14], *ws2 = (const float*)d_in[15];
    const float *wi = (const float*)d_in[16], *bi = (const float*)d_in[17],
                *gi = (const float*)d_in[18], *ei = (const float*)d_in[19];
    const float *wk = (const float*)d_in[20], *bk = (const float*)d_in[21];   // k before q!
    const float *wq = (const float*)d_in[22], *bq = (const float*)d_in[23];
    const float *wm = (const float*)d_in[24], *bm = (const float*)d_in[25],
                *gm = (const float*)d_in[26], *em = (const float*)d_in[27];
    const float *wd1 = (const float*)d_in[28], *bd1 = (const float*)d_in[29],
                *gd1 = (const float*)d_in[30], *ed1 = (const float*)d_in[31];
    const float *wd2 = (const float*)d_in[32], *bd2 = (const float*)d_in[33],
                *gd2 = (const float*)d_in[34], *ed2 = (const float*)d_in[35];
    const float *wc = (const float*)d_in[36], *bc = (const float*)d_in[37];
    float* out = (float*)d_out;

    // workspace (bytes), ~25.2 MB
    char* w8 = (char*)d_ws;
    bf16*  actA   = (bf16*)(w8);                    // 11,960,320
    bf16*  actB   = (bf16*)(w8 + 11960320);         // 11,960,320
    bf16*  whi    = (bf16*)(w8 + 23920640);         //    344,064
    bf16*  wlo    = (bf16*)(w8 + 24264704);         //    344,064
    float* tab    = (float*)(w8 + 24608768);        //    435,200
    float* stats  = (float*)(w8 + 25043968);        //      8,192
    float* bqk    = (float*)(w8 + 25052160);        //      1,024
    float* yvb    = (float*)(w8 + 25053184);        //     65,536

    prep_kernel<<<1106, 256, 0, stream>>>(stats, w2, w3, wi, wq, wk, whi, wlo, tab, bq, bk, bqk);
    // L1: 10 -> 64 (f32 A)  -> Y1 = actB (ld 64) + stats1
    gemm_l1_kernel<<<365, 256, 0, stream>>>(x, w1, b1, actB, stats);
    // L2: 64 -> 128, fused BN1 on A  -> Y2 = actA (ld 128) + stats2
    mfma_gemm<true><<<dim3(365, 2), 256, 0, stream>>>(actB, 64, whi, wlo, b2,
                                                      actA, 128, stats + 512, stats, g1, e1);
    // L3: 128 -> 256, fused BN2 on A -> Y3 = actB (ld 256) + stats3
    mfma_gemm<true><<<dim3(365, 4), 256, 0, stream>>>(actA, 128, whi + 8192, wlo + 8192, b3,
                                                      actB, 256, stats + 1024, stats + 512, g2, e2);
    // bn3 + pool + SE + residual -> rout = actA
    bnpoolse_kernel<<<64, 256, 0, stream>>>(actB, stats + 1024, g3, e3, ws1, ws2, actA);
    // inconv: 256 -> 256 -> Yi = actB + statsi
    mfma_gemm<false><<<dim3(365, 4), 256, 0, stream>>>(actA, 256, whi + 40960, wlo + 40960, bi,
                                                       actB, 256, stats + 1536, nullptr, nullptr, nullptr);
    // bn_i + relu + positional add -> e = actA
    bnrelu8_kernel<<<BT * 256 / 2048, 256, 0, stream>>>(actB, stats + 1536, gi, ei, actA, tab, pos);
    // q & k combined: 256 -> 256 (cols 0..127 = q, 128..255 = k) -> qk = actB
    mfma_gemm<false><<<dim3(365, 4), 256, 0, stream>>>(actA, 256, whi + 106496, wlo + 106496, bqk,
                                                       actB, 256, nullptr, nullptr, nullptr, nullptr);
    // fused attention (qk = actB, e = actA)
    attn_kernel<<<64, 256, 0, stream>>>(actB, actA, yvb);
    // fused tail
    tail_kernel<<<1, 1024, 0, stream>>>(yvb, wm, bm, gm, em, wd1, bd1, gd1, ed1,
                                        wd2, bd2, gd2, ed2, wc, bc, out);
}

// Round 7
// 397.777 us; speedup vs baseline: 1.6082x; 1.2353x over previous
//
#include <hip/hip_runtime.h>
#include <hip/hip_bf16.h>
#include <math.h>

#define TT 365
#define BT 23360
#define NPOS 425

typedef __hip_bfloat16 bf16;
typedef __attribute__((ext_vector_type(8))) short s16x8;
typedef __attribute__((ext_vector_type(4))) float f32x4;

__device__ __forceinline__ float b2f(bf16 v) { return __bfloat162float(v); }
__device__ __forceinline__ bf16  f2b(float v) { return __float2bfloat16(v); }
__device__ __forceinline__ float u2f(unsigned u) { return __uint_as_float(u); }
__device__ __forceinline__ short f2bs(float v) { bf16 h = __float2bfloat16(v); return *reinterpret_cast<short*>(&h); }
__device__ __forceinline__ void unpack8(uint4 raw, float* v) {
    v[0] = u2f(raw.x << 16); v[1] = u2f(raw.x & 0xffff0000u);
    v[2] = u2f(raw.y << 16); v[3] = u2f(raw.y & 0xffff0000u);
    v[4] = u2f(raw.z << 16); v[5] = u2f(raw.z & 0xffff0000u);
    v[6] = u2f(raw.w << 16); v[7] = u2f(raw.w & 0xffff0000u);
}

// ---------------- prep: zero stats+pooled, split-cast weights, pos table, concat q/k bias --------
// whi/wlo element offsets: w2@0(8192) w3@8192(32768) wi@40960(65536) wq@106496(32768) wk@139264(32768)
__global__ __launch_bounds__(256) void prep_kernel(
    float* __restrict__ stats, float* __restrict__ pooled,
    const float* __restrict__ w2, const float* __restrict__ w3, const float* __restrict__ wi,
    const float* __restrict__ wq, const float* __restrict__ wk,
    bf16* __restrict__ whi, bf16* __restrict__ wlo, float* __restrict__ tab,
    const float* __restrict__ bq, const float* __restrict__ bk, float* __restrict__ bqk)
{
    int i = blockIdx.x * 256 + threadIdx.x;
    if (i < 2048) { stats[i] = 0.f; return; } i -= 2048;
    if (i < 16384) { pooled[i] = 0.f; return; } i -= 16384;
    if (i < 172032) {
        float w;
        if      (i < 8192)   w = w2[i];
        else if (i < 40960)  w = w3[i - 8192];
        else if (i < 106496) w = wi[i - 40960];
        else if (i < 139264) w = wq[i - 106496];
        else                 w = wk[i - 139264];
        bf16 h = f2b(w);
        whi[i] = h;
        wlo[i] = f2b(w - b2f(h));
        return;
    } i -= 172032;
    if (i < 108800) {
        int c = i & 255, p = i >> 8;
        float e = (float)(2 * (c >> 1)) * (1.f / 256.f);
        float ang = (float)p * exp2f(-e * 9.96578428466209f);   // 1000^-e
        tab[i] = (c & 1) ? cosf(ang) : sinf(ang);
        return;
    } i -= 108800;
    if (i < 256) bqk[i] = (i < 128) ? bq[i] : bk[i - 128];
}

// ---------------- L1 GEMM (K=10, f32 A): Y[M,64](bf16) = x @ w1^T + b1; fused BN stats ----------
__global__ __launch_bounds__(256) void gemm_l1_kernel(
    const float* __restrict__ x,
    const float* __restrict__ W, const float* __restrict__ bias,
    bf16* __restrict__ Y, float* __restrict__ stats)
{
    const int t  = threadIdx.x;
    const int tx = t & 15, ty = t >> 4;
    const int row0 = blockIdx.x * 64;
    __shared__ float As[64][17];
    __shared__ float Ws[16][65];
    __shared__ float red_s[4][64];
    __shared__ float red_q[4][64];
    float acc[4][4];
#pragma unroll
    for (int rr = 0; rr < 4; ++rr)
#pragma unroll
        for (int cc = 0; cc < 4; ++cc) acc[rr][cc] = 0.f;
#pragma unroll
    for (int i = 0; i < 4; ++i) {
        int idx = t + i * 256, r = idx >> 4, c = idx & 15;
        As[r][c] = (c < 10) ? x[(size_t)(row0 + r) * 10 + c] : 0.f;
    }
#pragma unroll
    for (int i = 0; i < 4; ++i) {
        int idx = t + i * 256, c = idx >> 4, kk = idx & 15;
        Ws[kk][c] = (kk < 10) ? W[(size_t)c * 10 + kk] : 0.f;
    }
    __syncthreads();
#pragma unroll
    for (int kk = 0; kk < 10; ++kk) {
        float a[4];
#pragma unroll
        for (int rr = 0; rr < 4; ++rr) a[rr] = As[ty * 4 + rr][kk];
#pragma unroll
        for (int cc = 0; cc < 4; ++cc) {
            float w = Ws[kk][cc * 16 + tx];
#pragma unroll
            for (int rr = 0; rr < 4; ++rr) acc[rr][cc] = fmaf(a[rr], w, acc[rr][cc]);
        }
    }
    float s_cc[4], q_cc[4];
#pragma unroll
    for (int cc = 0; cc < 4; ++cc) { s_cc[cc] = 0.f; q_cc[cc] = 0.f; }
#pragma unroll
    for (int rr = 0; rr < 4; ++rr) {
        int row = row0 + ty * 4 + rr;
#pragma unroll
        for (int cc = 0; cc < 4; ++cc) {
            int col = cc * 16 + tx;
            float v = acc[rr][cc] + bias[col];
            Y[(size_t)row * 64 + col] = f2b(v);
            s_cc[cc] += v; q_cc[cc] += v * v;
        }
    }
    int w = t >> 6;
#pragma unroll
    for (int cc = 0; cc < 4; ++cc) {
        float s = s_cc[cc], q = q_cc[cc];
        s += __shfl_xor(s, 16); q += __shfl_xor(q, 16);
        s += __shfl_xor(s, 32); q += __shfl_xor(q, 32);
        if ((t & 63) < 16) { red_s[w][cc * 16 + tx] = s; red_q[w][cc * 16 + tx] = q; }
    }
    __syncthreads();
    if (t < 64) {
        float s = red_s[0][t] + red_s[1][t] + red_s[2][t] + red_s[3][t];
        float q = red_q[0][t] + red_q[1][t] + red_q[2][t] + red_q[3][t];
        atomicAdd(&stats[t], s);
        atomicAdd(&stats[256 + t], q);
    }
}

// ---------------- MFMA GEMM with fused A-operand transforms ----------------
// MODE 0: A raw bf16. MODE 1: A = relu(bn(y)). MODE 2: A = relu(bn(y)) + se[b, k].
// 64 rows x 64 cols per block (4 waves x 16 rows); C: col=lane&15, row=quad*4+r.
template<int MODE>
__global__ __launch_bounds__(256) void mfma_gemm(
    const bf16* __restrict__ A, int K,
    const bf16* __restrict__ Whi, const bf16* __restrict__ Wlo,
    const float* __restrict__ bias,
    bf16* __restrict__ Y, int ldY, float* __restrict__ stats,
    const float* __restrict__ bnstats, const float* __restrict__ bng,
    const float* __restrict__ bnb, const float* __restrict__ sebuf)
{
    __shared__ float red_s[4][64];
    __shared__ float red_q[4][64];
    __shared__ float scb[MODE ? 256 : 1];
    __shared__ float shb[MODE ? 256 : 1];
    const int t = threadIdx.x, wave = t >> 6, lane = t & 63;
    const int n16 = lane & 15, quad = lane >> 4;
    const int m0 = blockIdx.x * 64 + wave * 16;
    const int col0 = blockIdx.y * 64;
    if (MODE) {
        if (t < K) {
            float mu = bnstats[t] * (1.f / (float)BT);
            float var = bnstats[256 + t] * (1.f / (float)BT) - mu * mu;
            float sc = rsqrtf(var + 1e-5f) * bng[t];
            scb[t] = sc; shb[t] = bnb[t] - mu * sc;
        }
        __syncthreads();
    }
    const int arow = m0 + n16;
    const float* sev = (MODE == 2) ? (sebuf + (arow / TT) * 256) : nullptr;
    f32x4 acc[4];
    f32x4 zero = {0.f, 0.f, 0.f, 0.f};
#pragma unroll
    for (int ct = 0; ct < 4; ++ct) acc[ct] = zero;
    const bf16* Ap = A + (size_t)arow * K + quad * 8;
    const size_t wbase = (size_t)(col0 + n16) * K + quad * 8;
#pragma unroll 2
    for (int k0 = 0; k0 < K; k0 += 32) {
        s16x8 af;
        if (MODE) {
            s16x8 raw = *(const s16x8*)(Ap + k0);
            int kb = k0 + quad * 8;
#pragma unroll
            for (int j = 0; j < 8; ++j) {
                float y = u2f(((unsigned)(unsigned short)raw[j]) << 16);
                float v = fmaxf(fmaf(y, scb[kb + j], shb[kb + j]), 0.f);
                if (MODE == 2) v += sev[kb + j];
                af[j] = f2bs(v);
            }
        } else {
            af = *(const s16x8*)(Ap + k0);
        }
#pragma unroll
        for (int ct = 0; ct < 4; ++ct) {
            size_t wo = wbase + (size_t)ct * 16 * K + k0;
            s16x8 bl = *(const s16x8*)(Wlo + wo);
            s16x8 bh = *(const s16x8*)(Whi + wo);
            acc[ct] = __builtin_amdgcn_mfma_f32_16x16x32_bf16(af, bl, acc[ct], 0, 0, 0);
            acc[ct] = __builtin_amdgcn_mfma_f32_16x16x32_bf16(af, bh, acc[ct], 0, 0, 0);
        }
    }
#pragma unroll
    for (int ct = 0; ct < 4; ++ct) {
        int col = col0 + ct * 16 + n16;
        float bv = bias[col];
        float s = 0.f, q = 0.f;
#pragma unroll
        for (int r = 0; r < 4; ++r) {
            float v = acc[ct][r] + bv;
            int row = m0 + quad * 4 + r;
            Y[(size_t)row * ldY + col] = f2b(v);
            s += v; q += v * v;
        }
        s += __shfl_xor(s, 16); q += __shfl_xor(q, 16);
        s += __shfl_xor(s, 32); q += __shfl_xor(q, 32);
        if (quad == 0) { red_s[wave][ct * 16 + n16] = s; red_q[wave][ct * 16 + n16] = q; }
    }
    if (stats) {
        __syncthreads();
        if (t < 64) {
            float s = red_s[0][t] + red_s[1][t] + red_s[2][t] + red_s[3][t];
            float q = red_q[0][t] + red_q[1][t] + red_q[2][t] + red_q[3][t];
            atomicAdd(&stats[col0 + t], s);
            atomicAdd(&stats[256 + col0 + t], q);
        }
    }
}

// ---------------- pool partial: pooled[b,f] += sum_{rows in slice} relu(bn3(Y3)) ----------------
__global__ __launch_bounds__(256) void pool_partial_kernel(
    const bf16* __restrict__ Y3, const float* __restrict__ stats,
    const float* __restrict__ g3, const float* __restrict__ e3,
    float* __restrict__ pooled)
{
    const int b = blockIdx.x, part = blockIdx.y, t = threadIdx.x;
    const int cg = t & 31, rs = t >> 5;   // col-group (8 cols), row-slice (8)
    __shared__ float scb[256], shb[256];
    __shared__ float pp[8][256];
    {
        float mu = stats[t] * (1.f / (float)BT);
        float var = stats[256 + t] * (1.f / (float)BT) - mu * mu;
        float sc = rsqrtf(var + 1e-5f) * g3[t];
        scb[t] = sc; shb[t] = e3[t] - mu * sc;
    }
    __syncthreads();
    float acc[8] = {0.f,0.f,0.f,0.f,0.f,0.f,0.f,0.f};
    const int r0 = part * 46;
#pragma unroll
    for (int i = 0; i < 6; ++i) {
        int l = rs + i * 8;
        int r = r0 + l;
        if (l < 46 && r < TT) {
            uint4 raw = *(const uint4*)(Y3 + ((size_t)b * TT + r) * 256 + cg * 8);
            float v[8];
            unpack8(raw, v);
#pragma unroll
            for (int j = 0; j < 8; ++j)
                acc[j] += fmaxf(fmaf(v[j], scb[cg * 8 + j], shb[cg * 8 + j]), 0.f);
        }
    }
#pragma unroll
    for (int j = 0; j < 8; ++j) pp[rs][cg * 8 + j] = acc[j];
    __syncthreads();
    float s = 0.f;
#pragma unroll
    for (int r = 0; r < 8; ++r) s += pp[r][t];
    atomicAdd(&pooled[b * 256 + t], s);
}

// ---------------- SE MLP: sebuf[b,f] = sigmoid(relu(mean@ws1^T)@ws2^T) * mean ----------------
__global__ __launch_bounds__(256) void se_mlp_kernel(const float* __restrict__ pooled,
                                                     const float* __restrict__ ws1,
                                                     const float* __restrict__ ws2,
                                                     float* __restrict__ se) {
    int b = blockIdx.x, f = threadIdx.x;
    __shared__ float pl[256];
    __shared__ float hidden[16];
    float p = pooled[b * 256 + f] * (1.f / (float)TT);
    pl[f] = p;
    __syncthreads();
    if (f < 16) {
        float h = 0.f;
        for (int k2 = 0; k2 < 256; ++k2) h = fmaf(pl[k2], ws1[f * 256 + k2], h);
        hidden[f] = fmaxf(h, 0.f);
    }
    __syncthreads();
    float a = 0.f;
    for (int k2 = 0; k2 < 16; ++k2) a = fmaf(hidden[k2], ws2[f * 16 + k2], a);
    a = 1.f / (1.f + expf(-a));
    se[b * 256 + f] = a * p;
}

// ---------------- BN + ReLU + positional add (inconv output -> e), 8 elems/thread ----------------
__global__ __launch_bounds__(256) void bnrelu8_kernel(
    const bf16* __restrict__ Y, const float* __restrict__ stats,
    const float* __restrict__ g, const float* __restrict__ beta,
    bf16* __restrict__ Out, const float* __restrict__ tab, const int* __restrict__ pos) {
    int i = (blockIdx.x * 256 + threadIdx.x) * 8;
    int col = i & 255, row = i >> 8;
    uint4 raw = *(const uint4*)(Y + i);
    float v[8];
    unpack8(raw, v);
    const float invM = 1.f / (float)BT;
    const float* tr = tab + pos[row] * 256 + col;
    bf16 tmp[8] __attribute__((aligned(16)));
#pragma unroll
    for (int j = 0; j < 8; ++j) {
        float mu  = stats[col + j] * invM;
        float var = stats[256 + col + j] * invM - mu * mu;
        float o = (v[j] - mu) * rsqrtf(var + 1e-5f) * g[col + j] + beta[col + j];
        tmp[j] = f2b(fmaxf(o, 0.f) + tr[j]);
    }
    *(uint4*)(Out + i) = *(const uint4*)tmp;
}

// ---------------- attention: one wave per (b,h); qk[BT,256] (q 0:128, k 128:256) ----------------
__global__ __launch_bounds__(64) void attn_kernel(
    const bf16* __restrict__ qk, const bf16* __restrict__ e, float* __restrict__ yv)
{
    __shared__ float aw[368];
    const int b = blockIdx.x, h = blockIdx.y;
    const int lane = threadIdx.x;
    const bf16* rowbase = qk + (size_t)b * TT * 256;
    // phase 1: ksum[8] over all rows
    float ks[8] = {0.f,0.f,0.f,0.f,0.f,0.f,0.f,0.f};
#pragma unroll
    for (int i = 0; i < 6; ++i) {
        int r = lane + i * 64;
        if (r < TT) {
            uint4 raw = *(const uint4*)(rowbase + (size_t)r * 256 + 128 + h * 8);
            float v[8];
            unpack8(raw, v);
#pragma unroll
            for (int j = 0; j < 8; ++j) ks[j] += v[j];
        }
    }
#pragma unroll
    for (int off = 1; off < 64; off <<= 1)
#pragma unroll
        for (int j = 0; j < 8; ++j) ks[j] += __shfl_xor(ks[j], off);
    // phase 2: scores for my 6 rows
    const float scale = 1.f / (sqrtf(8.f) * (float)TT);
    float sv[6];
    float m = -1e30f;
#pragma unroll
    for (int i = 0; i < 6; ++i) {
        int r = lane + i * 64;
        float s = -1e30f;
        if (r < TT) {
            uint4 raw = *(const uint4*)(rowbase + (size_t)r * 256 + h * 8);
            float v[8];
            unpack8(raw, v);
            float dot = 0.f;
#pragma unroll
            for (int j = 0; j < 8; ++j) dot = fmaf(v[j], ks[j], dot);
            s = dot * scale;
        }
        sv[i] = s;
        m = fmaxf(m, s);
    }
#pragma unroll
    for (int off = 1; off < 64; off <<= 1) m = fmaxf(m, __shfl_xor(m, off));
    float sum = 0.f;
#pragma unroll
    for (int i = 0; i < 6; ++i) {
        float ev = (sv[i] > -1e29f) ? expf(sv[i] - m) : 0.f;
        sv[i] = ev; sum += ev;
    }
#pragma unroll
    for (int off = 1; off < 64; off <<= 1) sum += __shfl_xor(sum, off);
    float inv = 1.f / sum;
#pragma unroll
    for (int i = 0; i < 6; ++i) {
        int r = lane + i * 64;
        if (r < TT) aw[r] = sv[i] * inv;
    }
    __syncthreads();
    // phase 4: yv[b, h*16 + half*8 + j] = sum_r aw[r] * e[b, r, col]
    const int half = lane & 1, rs = lane >> 1;   // 32 row-slices, 2 col-halves
    float acc[8] = {0.f,0.f,0.f,0.f,0.f,0.f,0.f,0.f};
    const bf16* ebase = e + (size_t)b * TT * 256 + h * 16 + half * 8;
#pragma unroll
    for (int i = 0; i < 12; ++i) {
        int r = rs + i * 32;
        if (r < TT) {
            uint4 raw = *(const uint4*)(ebase + (size_t)r * 256);
            float v[8];
            unpack8(raw, v);
            float a = aw[r];
#pragma unroll
            for (int j = 0; j < 8; ++j) acc[j] = fmaf(a, v[j], acc[j]);
        }
    }
#pragma unroll
    for (int off = 2; off < 64; off <<= 1)
#pragma unroll
        for (int j = 0; j < 8; ++j) acc[j] += __shfl_xor(acc[j], off);
    if (lane < 2) {
        float* op = yv + b * 256 + h * 16 + half * 8;
#pragma unroll
        for (int j = 0; j < 8; ++j) op[j] = acc[j];
    }
}

// ---------------- fused tail (round-6 version, weights staged in LDS) ----------------
__global__ __launch_bounds__(1024) void tail_kernel(
    const float* __restrict__ yv,
    const float* wm, const float* bm, const float* gm, const float* em,
    const float* wd1, const float* bd1, const float* gd1, const float* ed1,
    const float* wd2, const float* bd2, const float* gd2, const float* ed2,
    const float* wc, const float* bc, float* __restrict__ out)
{
    __shared__ float lds[12352];
    const int t = threadIdx.x;
    const int r = t & 63, cg = t >> 6;
    float* Xq  = lds;            // [64k][65]
    float* Wp  = lds + 4160;     // [128c][64k]
    float* Z1t = lds;            // [128c][64r]
    float* Wd1h = lds + 8192;    // [64c][64k]
    float* Z2t = lds;            // [64c][64r]
    float* Wd2 = lds + 4096;     // [32c][64k]
    float* Z3t = lds + 6144;     // [32c][64r]
    float* WcL = lds + 8192;     // [10c][32k]

    float acc1[8] = {0.f,0.f,0.f,0.f,0.f,0.f,0.f,0.f};
    const int c01 = cg * 8;
    for (int p = 0; p < 4; ++p) {
        __syncthreads();
        for (int i = t; i < 4096; i += 1024) {
            int kk = i & 63, rr = i >> 6;
            Xq[kk * 65 + rr] = yv[rr * 256 + p * 64 + kk];
        }
        {
            const float4* wm4 = (const float4*)wm;
            float4* Wp4 = (float4*)Wp;
            for (int i = t; i < 2048; i += 1024) {
                int kk4 = i & 15, c = i >> 4;
                Wp4[c * 16 + kk4] = wm4[c * 64 + p * 16 + kk4];
            }
        }
        __syncthreads();
#pragma unroll 4
        for (int k4 = 0; k4 < 16; ++k4) {
            float xv[4];
#pragma unroll
            for (int j = 0; j < 4; ++j) xv[j] = Xq[(k4 * 4 + j) * 65 + r];
#pragma unroll
            for (int c = 0; c < 8; ++c) {
                float4 w = *(const float4*)(Wp + (c01 + c) * 64 + k4 * 4);
                acc1[c] = fmaf(xv[0], w.x, acc1[c]);
                acc1[c] = fmaf(xv[1], w.y, acc1[c]);
                acc1[c] = fmaf(xv[2], w.z, acc1[c]);
                acc1[c] = fmaf(xv[3], w.w, acc1[c]);
            }
        }
    }
    float z1v[8];
#pragma unroll
    for (int c = 0; c < 8; ++c) {
        float v = acc1[c] + bm[c01 + c];
        float s = v, q = v * v;
#pragma unroll
        for (int off = 1; off < 64; off <<= 1) { s += __shfl_xor(s, off); q += __shfl_xor(q, off); }
        float mu = s * (1.f / 64.f), var = q * (1.f / 64.f) - mu * mu;
        z1v[c] = fmaxf((v - mu) * rsqrtf(var + 1e-5f) * gm[c01 + c] + em[c01 + c], 0.f);
    }
    __syncthreads();
#pragma unroll
    for (int c = 0; c < 8; ++c) Z1t[(c01 + c) * 64 + r] = z1v[c];
    float acc2[4] = {0.f, 0.f, 0.f, 0.f};
    const int c02 = cg * 4;
    for (int ph = 0; ph < 2; ++ph) {
        __syncthreads();
        {
            const float4* s4 = (const float4*)wd1;
            float4* d4 = (float4*)Wd1h;
            int kk4 = t & 15, c = t >> 4;
            d4[c * 16 + kk4] = s4[c * 32 + ph * 16 + kk4];
        }
        __syncthreads();
#pragma unroll 4
        for (int k4 = 0; k4 < 16; ++k4) {
            float xv[4];
#pragma unroll
            for (int j = 0; j < 4; ++j) xv[j] = Z1t[(ph * 64 + k4 * 4 + j) * 64 + r];
#pragma unroll
            for (int c = 0; c < 4; ++c) {
                float4 w = *(const float4*)(Wd1h + (c02 + c) * 64 + k4 * 4);
                acc2[c] = fmaf(xv[0], w.x, acc2[c]);
                acc2[c] = fmaf(xv[1], w.y, acc2[c]);
                acc2[c] = fmaf(xv[2], w.z, acc2[c]);
                acc2[c] = fmaf(xv[3], w.w, acc2[c]);
            }
        }
    }
    float z2v[4];
#pragma unroll
    for (int c = 0; c < 4; ++c) {
        float v = acc2[c] + bd1[c02 + c];
        float s = v, q = v * v;
#pragma unroll
        for (int off = 1; off < 64; off <<= 1) { s += __shfl_xor(s, off); q += __shfl_xor(q, off); }
        float mu = s * (1.f / 64.f), var = q * (1.f / 64.f) - mu * mu;
        z2v[c] = fmaxf((v - mu) * rsqrtf(var + 1e-5f) * gd1[c02 + c] + ed1[c02 + c], 0.f);
    }
    __syncthreads();
#pragma unroll
    for (int c = 0; c < 4; ++c) Z2t[(c02 + c) * 64 + r] = z2v[c];
    {
        const float4* s4 = (const float4*)wd2;
        float4* d4 = (float4*)Wd2;
        if (t < 512) d4[t] = s4[t];
    }
    __syncthreads();
    float acc3[2] = {0.f, 0.f};
    const int c03 = cg * 2;
#pragma unroll 4
    for (int k4 = 0; k4 < 16; ++k4) {
        float xv[4];
#pragma unroll
        for (int j = 0; j < 4; ++j) xv[j] = Z2t[(k4 * 4 + j) * 64 + r];
#pragma unroll
        for (int c = 0; c < 2; ++c) {
            float4 w = *(const float4*)(Wd2 + (c03 + c) * 64 + k4 * 4);
            acc3[c] = fmaf(xv[0], w.x, acc3[c]);
            acc3[c] = fmaf(xv[1], w.y, acc3[c]);
            acc3[c] = fmaf(xv[2], w.z, acc3[c]);
            acc3[c] = fmaf(xv[3], w.w, acc3[c]);
        }
    }
#pragma unroll
    for (int c = 0; c < 2; ++c) {
        float v = acc3[c] + bd2[c03 + c];
        float s = v, q = v * v;
#pragma unroll
        for (int off = 1; off < 64; off <<= 1) { s += __shfl_xor(s, off); q += __shfl_xor(q, off); }
        float mu = s * (1.f / 64.f), var = q * (1.f / 64.f) - mu * mu;
        Z3t[(c03 + c) * 64 + r] = fmaxf((v - mu) * rsqrtf(var + 1e-5f) * gd2[c03 + c] + ed2[c03 + c], 0.f);
    }
    if (t < 80) ((float4*)WcL)[t] = ((const float4*)wc)[t];
    __syncthreads();
    if (t < 640) {
        int rr = t / 10, c = t % 10;
        float s = bc[c];
#pragma unroll
        for (int kk = 0; kk < 32; ++kk) s = fmaf(Z3t[kk * 64 + rr], WcL[c * 32 + kk], s);
        out[t] = s;
    }
}

// ---------------- launch ----------------

extern "C" void kernel_launch(void* const* d_in, const int* in_sizes, int n_in,
                              void* d_out, int out_size, void* d_ws, size_t ws_size,
                              hipStream_t stream) {
    (void)in_sizes; (void)n_in; (void)out_size; (void)ws_size;
    const float* x  = (const float*)d_in[0];
    const int* pos  = (const int*)d_in[1];
    const float *w1 = (const float*)d_in[2],  *b1 = (const float*)d_in[3],
                *g1 = (const float*)d_in[4],  *e1 = (const float*)d_in[5];
    const float *w2 = (const float*)d_in[6],  *b2 = (const float*)d_in[7],
                *g2 = (const float*)d_in[8],  *e2 = (const float*)d_in[9];
    const float *w3 = (const float*)d_in[10], *b3 = (const float*)d_in[11],
                *g3 = (const float*)d_in[12], *e3 = (const float*)d_in[13];
    const float *ws1 = (const float*)d_in[14], *ws2 = (const float*)d_in[15];
    const float *wi = (const float*)d_in[16], *bi = (const float*)d_in[17],
                *gi = (const float*)d_in[18], *ei = (const float*)d_in[19];
    const float *wk = (const float*)d_in[20], *bk = (const float*)d_in[21];   // k before q!
    const float *wq = (const float*)d_in[22], *bq = (const float*)d_in[23];
    const float *wm = (const float*)d_in[24], *bm = (const float*)d_in[25],
                *gm = (const float*)d_in[26], *em = (const float*)d_in[27];
    const float *wd1 = (const float*)d_in[28], *bd1 = (const float*)d_in[29],
                *gd1 = (const float*)d_in[30], *ed1 = (const float*)d_in[31];
    const float *wd2 = (const float*)d_in[32], *bd2 = (const float*)d_in[33],
                *gd2 = (const float*)d_in[34], *ed2 = (const float*)d_in[35];
    const float *wc = (const float*)d_in[36], *bc = (const float*)d_in[37];
    float* out = (float*)d_out;

    char* w8 = (char*)d_ws;
    bf16*  actA   = (bf16*)(w8);                    // 11,960,320
    bf16*  actB   = (bf16*)(w8 + 11960320);         // 11,960,320
    bf16*  whi    = (bf16*)(w8 + 23920640);         //    344,064
    bf16*  wlo    = (bf16*)(w8 + 24264704);         //    344,064
    float* tab    = (float*)(w8 + 24608768);        //    435,200
    float* stats  = (float*)(w8 + 25043968);        //      8,192
    float* bqk    = (float*)(w8 + 25052160);        //      1,024
    float* pooled = (float*)(w8 + 25053184);        //     65,536
    float* sebuf  = (float*)(w8 + 25118720);        //     65,536
    float* yvb    = (float*)(w8 + 25184256);        //     65,536

    prep_kernel<<<1170, 256, 0, stream>>>(stats, pooled, w2, w3, wi, wq, wk, whi, wlo, tab, bq, bk, bqk);
    // L1: 10 -> 64 -> Y1 = actB + stats1
    gemm_l1_kernel<<<365, 256, 0, stream>>>(x, w1, b1, actB, stats);
    // L2: 64 -> 128, fused BN1 -> Y2 = actA + stats2
    mfma_gemm<1><<<dim3(365, 2), 256, 0, stream>>>(actB, 64, whi, wlo, b2,
                                                   actA, 128, stats + 512, stats, g1, e1, nullptr);
    // L3: 128 -> 256, fused BN2 -> Y3 = actB + stats3
    mfma_gemm<1><<<dim3(365, 4), 256, 0, stream>>>(actA, 128, whi + 8192, wlo + 8192, b3,
                                                   actB, 256, stats + 1024, stats + 512, g2, e2, nullptr);
    // pool (fused BN3+relu) -> pooled; SE MLP -> sebuf
    pool_partial_kernel<<<dim3(64, 8), 256, 0, stream>>>(actB, stats + 1024, g3, e3, pooled);
    se_mlp_kernel<<<64, 256, 0, stream>>>(pooled, ws1, ws2, sebuf);
    // inconv: A = Y3 with fused BN3+relu+SE-residual -> Yi = actA + statsi
    mfma_gemm<2><<<dim3(365, 4), 256, 0, stream>>>(actB, 256, whi + 40960, wlo + 40960, bi,
                                                   actA, 256, stats + 1536, stats + 1024, g3, e3, sebuf);
    // bn_i + relu + PE -> e = actB
    bnrelu8_kernel<<<BT * 256 / 2048, 256, 0, stream>>>(actA, stats + 1536, gi, ei, actB, tab, pos);
    // q & k combined: 256 -> 256 -> qk = actA
    mfma_gemm<0><<<dim3(365, 4), 256, 0, stream>>>(actB, 256, whi + 106496, wlo + 106496, bqk,
                                                   actA, 256, nullptr, nullptr, nullptr, nullptr, nullptr);
    // attention: one wave per (b,h)
    attn_kernel<<<dim3(64, 16), 64, 0, stream>>>(actA, actB, yvb);
    // fused tail
    tail_kernel<<<1, 1024, 0, stream>>>(yvb, wm, bm, gm, em, wd1, bd1, gd1, ed1,
                                        wd2, bd2, gd2, ed2, wc, bc, out);
}

// Round 8
// 318.554 us; speedup vs baseline: 2.0081x; 1.2487x over previous
//
#include <hip/hip_runtime.h>
#include <hip/hip_bf16.h>
#include <math.h>

#define TT 365
#define BT 23360
#define NPOS 425

typedef __hip_bfloat16 bf16;
typedef __attribute__((ext_vector_type(8))) short s16x8;
typedef __attribute__((ext_vector_type(4))) float f32x4;

__device__ __forceinline__ float b2f(bf16 v) { return __bfloat162float(v); }
__device__ __forceinline__ bf16  f2b(float v) { return __float2bfloat16(v); }
__device__ __forceinline__ float u2f(unsigned u) { return __uint_as_float(u); }
__device__ __forceinline__ short f2bs(float v) { bf16 h = __float2bfloat16(v); return *reinterpret_cast<short*>(&h); }
__device__ __forceinline__ void unpack8(uint4 raw, float* v) {
    v[0] = u2f(raw.x << 16); v[1] = u2f(raw.x & 0xffff0000u);
    v[2] = u2f(raw.y << 16); v[3] = u2f(raw.y & 0xffff0000u);
    v[4] = u2f(raw.z << 16); v[5] = u2f(raw.z & 0xffff0000u);
    v[6] = u2f(raw.w << 16); v[7] = u2f(raw.w & 0xffff0000u);
}

// ---------------- prep: zero stats/pooled/esum, split-cast weights, pos table --------------------
// whi/wlo element offsets: w2@0(8192) w3@8192(32768) wi@40960(65536) wq@106496(32768); total 139264
__global__ __launch_bounds__(256) void prep_kernel(
    float* __restrict__ stats, float* __restrict__ pooled, float* __restrict__ esum,
    const float* __restrict__ w2, const float* __restrict__ w3, const float* __restrict__ wi,
    const float* __restrict__ wq,
    bf16* __restrict__ whi, bf16* __restrict__ wlo, float* __restrict__ tab)
{
    int i = blockIdx.x * 256 + threadIdx.x;
    if (i < 2048)  { stats[i] = 0.f; return; }  i -= 2048;
    if (i < 16384) { pooled[i] = 0.f; return; } i -= 16384;
    if (i < 16384) { esum[i] = 0.f; return; }   i -= 16384;
    if (i < 139264) {
        float w;
        if      (i < 8192)   w = w2[i];
        else if (i < 40960)  w = w3[i - 8192];
        else if (i < 106496) w = wi[i - 40960];
        else                 w = wq[i - 106496];
        bf16 h = f2b(w);
        whi[i] = h;
        wlo[i] = f2b(w - b2f(h));
        return;
    } i -= 139264;
    if (i < 108800) {
        int c = i & 255, p = i >> 8;
        float e = (float)(2 * (c >> 1)) * (1.f / 256.f);
        float ang = (float)p * exp2f(-e * 9.96578428466209f);   // 1000^-e
        tab[i] = (c & 1) ? cosf(ang) : sinf(ang);
    }
}

// ---------------- L1 GEMM (K=10, f32 A): Y[M,64](bf16) = x @ w1^T + b1; fused BN stats ----------
__global__ __launch_bounds__(256) void gemm_l1_kernel(
    const float* __restrict__ x,
    const float* __restrict__ W, const float* __restrict__ bias,
    bf16* __restrict__ Y, float* __restrict__ stats)
{
    const int t  = threadIdx.x;
    const int tx = t & 15, ty = t >> 4;
    const int row0 = blockIdx.x * 64;
    __shared__ float As[64][17];
    __shared__ float Ws[16][65];
    __shared__ float red_s[4][64];
    __shared__ float red_q[4][64];
    float acc[4][4];
#pragma unroll
    for (int rr = 0; rr < 4; ++rr)
#pragma unroll
        for (int cc = 0; cc < 4; ++cc) acc[rr][cc] = 0.f;
#pragma unroll
    for (int i = 0; i < 4; ++i) {
        int idx = t + i * 256, r = idx >> 4, c = idx & 15;
        As[r][c] = (c < 10) ? x[(size_t)(row0 + r) * 10 + c] : 0.f;
    }
#pragma unroll
    for (int i = 0; i < 4; ++i) {
        int idx = t + i * 256, c = idx >> 4, kk = idx & 15;
        Ws[kk][c] = (kk < 10) ? W[(size_t)c * 10 + kk] : 0.f;
    }
    __syncthreads();
#pragma unroll
    for (int kk = 0; kk < 10; ++kk) {
        float a[4];
#pragma unroll
        for (int rr = 0; rr < 4; ++rr) a[rr] = As[ty * 4 + rr][kk];
#pragma unroll
        for (int cc = 0; cc < 4; ++cc) {
            float w = Ws[kk][cc * 16 + tx];
#pragma unroll
            for (int rr = 0; rr < 4; ++rr) acc[rr][cc] = fmaf(a[rr], w, acc[rr][cc]);
        }
    }
    float s_cc[4], q_cc[4];
#pragma unroll
    for (int cc = 0; cc < 4; ++cc) { s_cc[cc] = 0.f; q_cc[cc] = 0.f; }
#pragma unroll
    for (int rr = 0; rr < 4; ++rr) {
        int row = row0 + ty * 4 + rr;
#pragma unroll
        for (int cc = 0; cc < 4; ++cc) {
            int col = cc * 16 + tx;
            float v = acc[rr][cc] + bias[col];
            Y[(size_t)row * 64 + col] = f2b(v);
            s_cc[cc] += v; q_cc[cc] += v * v;
        }
    }
    int w = t >> 6;
#pragma unroll
    for (int cc = 0; cc < 4; ++cc) {
        float s = s_cc[cc], q = q_cc[cc];
        s += __shfl_xor(s, 16); q += __shfl_xor(q, 16);
        s += __shfl_xor(s, 32); q += __shfl_xor(q, 32);
        if ((t & 63) < 16) { red_s[w][cc * 16 + tx] = s; red_q[w][cc * 16 + tx] = q; }
    }
    __syncthreads();
    if (t < 64) {
        float s = red_s[0][t] + red_s[1][t] + red_s[2][t] + red_s[3][t];
        float q = red_q[0][t] + red_q[1][t] + red_q[2][t] + red_q[3][t];
        atomicAdd(&stats[t], s);
        atomicAdd(&stats[256 + t], q);
    }
}

// ---------------- MFMA GEMM, LDS-staged W, A prefetched to registers ----------------
// MODE 0: A raw. MODE 1: A = relu(bn(y)). MODE 2: A = relu(bn(y)) + se[b,k].
// Block: 256 thr = 4 waves x 16 rows, 64 cols. W staged per KC-chunk as [kgroup][col][8 bf16].
template<int MODE, int K>
__global__ __launch_bounds__(256) void mfma_gemm(
    const bf16* __restrict__ A,
    const bf16* __restrict__ Whi, const bf16* __restrict__ Wlo,
    const float* __restrict__ bias,
    bf16* __restrict__ Y, int ldY, float* __restrict__ stats,
    const float* __restrict__ bnstats, const float* __restrict__ bng,
    const float* __restrict__ bnb, const float* __restrict__ sebuf)
{
    constexpr int KC = (K > 128) ? 128 : K;      // staged chunk
    __shared__ s16x8 Wl[2][KC / 8][64];          // [hi/lo][kgroup][col]
    __shared__ float red_s[4][64];
    __shared__ float red_q[4][64];
    __shared__ float scb[MODE ? K : 1];
    __shared__ float shb[MODE ? K : 1];
    const int t = threadIdx.x, wave = t >> 6, lane = t & 63;
    const int n16 = lane & 15, quad = lane >> 4;
    const int m0 = blockIdx.x * 64 + wave * 16;
    const int col0 = blockIdx.y * 64;
    const int sc_ = t & 63, skg0 = t >> 6;       // staging roles
    const bf16* gh = Whi + (size_t)(col0 + sc_) * K;
    const bf16* gl = Wlo + (size_t)(col0 + sc_) * K;
    // stage chunk 0 + BN coeffs
#pragma unroll
    for (int kg = skg0; kg < KC / 8; kg += 4) {
        Wl[0][kg][sc_] = *(const s16x8*)(gh + kg * 8);
        Wl[1][kg][sc_] = *(const s16x8*)(gl + kg * 8);
    }
    if (MODE) {
        if (t < K) {
            float mu = bnstats[t] * (1.f / (float)BT);
            float var = bnstats[256 + t] * (1.f / (float)BT) - mu * mu;
            float sc = rsqrtf(var + 1e-5f) * bng[t];
            scb[t] = sc; shb[t] = bnb[t] - mu * sc;
        }
    }
    __syncthreads();
    // prefetch + transform all A fragments
    const int arow = m0 + n16;
    const float* sev = (MODE == 2) ? (sebuf + (arow / TT) * 256) : nullptr;
    const bf16* Ap = A + (size_t)arow * K + quad * 8;
    s16x8 af[K / 32];
#pragma unroll
    for (int i = 0; i < K / 32; ++i) {
        s16x8 raw = *(const s16x8*)(Ap + i * 32);
        if (MODE) {
            int kb = i * 32 + quad * 8;
#pragma unroll
            for (int j = 0; j < 8; ++j) {
                float y = u2f(((unsigned)(unsigned short)raw[j]) << 16);
                float v = fmaxf(fmaf(y, scb[kb + j], shb[kb + j]), 0.f);
                if (MODE == 2) v += sev[kb + j];
                raw[j] = f2bs(v);
            }
        }
        af[i] = raw;
    }
    f32x4 acc[4];
    f32x4 zero = {0.f, 0.f, 0.f, 0.f};
#pragma unroll
    for (int ct = 0; ct < 4; ++ct) acc[ct] = zero;
    // K loop over staged chunks
#pragma unroll
    for (int kc = 0; kc < K; kc += KC) {
        if (kc) {
            __syncthreads();   // all waves done with previous chunk
#pragma unroll
            for (int kg = skg0; kg < KC / 8; kg += 4) {
                Wl[0][kg][sc_] = *(const s16x8*)(gh + kc + kg * 8);
                Wl[1][kg][sc_] = *(const s16x8*)(gl + kc + kg * 8);
            }
            __syncthreads();
        }
#pragma unroll
        for (int i = 0; i < KC / 32; ++i) {
            const int kgq = i * 4 + quad;
            const s16x8 a = af[(kc >> 5) + i];
#pragma unroll
            for (int ct = 0; ct < 4; ++ct) {
                s16x8 bl = Wl[1][kgq][ct * 16 + n16];
                s16x8 bh = Wl[0][kgq][ct * 16 + n16];
                acc[ct] = __builtin_amdgcn_mfma_f32_16x16x32_bf16(a, bl, acc[ct], 0, 0, 0);
                acc[ct] = __builtin_amdgcn_mfma_f32_16x16x32_bf16(a, bh, acc[ct], 0, 0, 0);
            }
        }
    }
    // epilogue: bias, store, BN stats
#pragma unroll
    for (int ct = 0; ct < 4; ++ct) {
        int col = col0 + ct * 16 + n16;
        float bv = bias[col];
        float s = 0.f, q = 0.f;
#pragma unroll
        for (int r = 0; r < 4; ++r) {
            float v = acc[ct][r] + bv;
            int row = m0 + quad * 4 + r;
            Y[(size_t)row * ldY + col] = f2b(v);
            s += v; q += v * v;
        }
        s += __shfl_xor(s, 16); q += __shfl_xor(q, 16);
        s += __shfl_xor(s, 32); q += __shfl_xor(q, 32);
        if (quad == 0) { red_s[wave][ct * 16 + n16] = s; red_q[wave][ct * 16 + n16] = q; }
    }
    if (stats) {
        __syncthreads();
        if (t < 64) {
            float s = red_s[0][t] + red_s[1][t] + red_s[2][t] + red_s[3][t];
            float q = red_q[0][t] + red_q[1][t] + red_q[2][t] + red_q[3][t];
            atomicAdd(&stats[col0 + t], s);
            atomicAdd(&stats[256 + col0 + t], q);
        }
    }
}

// ---------------- pool partial: pooled[b,f] += sum_rows relu(bn3(Y3)) ----------------
__global__ __launch_bounds__(256) void pool_partial_kernel(
    const bf16* __restrict__ Y3, const float* __restrict__ stats,
    const float* __restrict__ g3, const float* __restrict__ e3,
    float* __restrict__ pooled)
{
    const int b = blockIdx.x, part = blockIdx.y, t = threadIdx.x;
    const int cg = t & 31, rs = t >> 5;
    __shared__ float scb[256], shb[256];
    __shared__ float pp[8][256];
    {
        float mu = stats[t] * (1.f / (float)BT);
        float var = stats[256 + t] * (1.f / (float)BT) - mu * mu;
        float sc = rsqrtf(var + 1e-5f) * g3[t];
        scb[t] = sc; shb[t] = e3[t] - mu * sc;
    }
    __syncthreads();
    float acc[8] = {0.f,0.f,0.f,0.f,0.f,0.f,0.f,0.f};
    const int r0 = part * 46;
#pragma unroll
    for (int i = 0; i < 6; ++i) {
        int l = rs + i * 8;
        int r = r0 + l;
        if (l < 46 && r < TT) {
            uint4 raw = *(const uint4*)(Y3 + ((size_t)b * TT + r) * 256 + cg * 8);
            float v[8];
            unpack8(raw, v);
#pragma unroll
            for (int j = 0; j < 8; ++j)
                acc[j] += fmaxf(fmaf(v[j], scb[cg * 8 + j], shb[cg * 8 + j]), 0.f);
        }
    }
#pragma unroll
    for (int j = 0; j < 8; ++j) pp[rs][cg * 8 + j] = acc[j];
    __syncthreads();
    float s = 0.f;
#pragma unroll
    for (int r = 0; r < 8; ++r) s += pp[r][t];
    atomicAdd(&pooled[b * 256 + t], s);
}

// ---------------- esum partial: esum[b,f] += sum_rows e ----------------
__global__ __launch_bounds__(256) void esum_kernel(const bf16* __restrict__ e,
                                                   float* __restrict__ esum)
{
    const int b = blockIdx.x, part = blockIdx.y, t = threadIdx.x;
    const int cg = t & 31, rs = t >> 5;
    __shared__ float pp[8][256];
    float acc[8] = {0.f,0.f,0.f,0.f,0.f,0.f,0.f,0.f};
    const int r0 = part * 46;
#pragma unroll
    for (int i = 0; i < 6; ++i) {
        int l = rs + i * 8;
        int r = r0 + l;
        if (l < 46 && r < TT) {
            uint4 raw = *(const uint4*)(e + ((size_t)b * TT + r) * 256 + cg * 8);
            float v[8];
            unpack8(raw, v);
#pragma unroll
            for (int j = 0; j < 8; ++j) acc[j] += v[j];
        }
    }
#pragma unroll
    for (int j = 0; j < 8; ++j) pp[rs][cg * 8 + j] = acc[j];
    __syncthreads();
    float s = 0.f;
#pragma unroll
    for (int r = 0; r < 8; ++r) s += pp[r][t];
    atomicAdd(&esum[b * 256 + t], s);
}

// ---------------- SE MLP ----------------
__global__ __launch_bounds__(256) void se_mlp_kernel(const float* __restrict__ pooled,
                                                     const float* __restrict__ ws1,
                                                     const float* __restrict__ ws2,
                                                     float* __restrict__ se) {
    int b = blockIdx.x, f = threadIdx.x;
    __shared__ float pl[256];
    __shared__ float hidden[16];
    float p = pooled[b * 256 + f] * (1.f / (float)TT);
    pl[f] = p;
    __syncthreads();
    if (f < 16) {
        float h = 0.f;
        for (int k2 = 0; k2 < 256; ++k2) h = fmaf(pl[k2], ws1[f * 256 + k2], h);
        hidden[f] = fmaxf(h, 0.f);
    }
    __syncthreads();
    float a = 0.f;
    for (int k2 = 0; k2 < 16; ++k2) a = fmaf(hidden[k2], ws2[f * 16 + k2], a);
    a = 1.f / (1.f + expf(-a));
    se[b * 256 + f] = a * p;
}

// ---------------- BN + ReLU + positional add (inconv output -> e), 8 elems/thread ----------------
__global__ __launch_bounds__(256) void bnrelu8_kernel(
    const bf16* __restrict__ Y, const float* __restrict__ stats,
    const float* __restrict__ g, const float* __restrict__ beta,
    bf16* __restrict__ Out, const float* __restrict__ tab, const int* __restrict__ pos) {
    int i = (blockIdx.x * 256 + threadIdx.x) * 8;
    int col = i & 255, row = i >> 8;
    uint4 raw = *(const uint4*)(Y + i);
    float v[8];
    unpack8(raw, v);
    const float invM = 1.f / (float)BT;
    const float* tr = tab + pos[row] * 256 + col;
    bf16 tmp[8] __attribute__((aligned(16)));
#pragma unroll
    for (int j = 0; j < 8; ++j) {
        float mu  = stats[col + j] * invM;
        float var = stats[256 + col + j] * invM - mu * mu;
        float o = (v[j] - mu) * rsqrtf(var + 1e-5f) * g[col + j] + beta[col + j];
        tmp[j] = f2b(fmaxf(o, 0.f) + tr[j]);
    }
    *(uint4*)(Out + i) = *(const uint4*)tmp;
}

// ---------------- attention: one wave per (b,h); ksum = esum.wk_h^T + T*bk ----------------
__global__ __launch_bounds__(64) void attn_kernel(
    const bf16* __restrict__ q, const bf16* __restrict__ e,
    const float* __restrict__ esum, const float* __restrict__ wk,
    const float* __restrict__ bk, float* __restrict__ yv)
{
    __shared__ float aw[368];
    const int b = blockIdx.x, h = blockIdx.y;
    const int lane = threadIdx.x;
    // ksum[8] from esum (lane covers cols lane*4..+4)
    float4 es = *(const float4*)(esum + b * 256 + lane * 4);
    float ks[8];
#pragma unroll
    for (int d = 0; d < 8; ++d) {
        float4 wv = *(const float4*)(wk + (size_t)(h * 8 + d) * 256 + lane * 4);
        ks[d] = es.x * wv.x + es.y * wv.y + es.z * wv.z + es.w * wv.w;
    }
#pragma unroll
    for (int off = 1; off < 64; off <<= 1)
#pragma unroll
        for (int d = 0; d < 8; ++d) ks[d] += __shfl_xor(ks[d], off);
#pragma unroll
    for (int d = 0; d < 8; ++d) ks[d] += (float)TT * bk[h * 8 + d];
    // scores for my 6 rows (q is [BT,128])
    const float scale = 1.f / (sqrtf(8.f) * (float)TT);
    const bf16* qb = q + (size_t)b * TT * 128 + h * 8;
    float sv[6];
    float m = -1e30f;
#pragma unroll
    for (int i = 0; i < 6; ++i) {
        int r = lane + i * 64;
        float s = -1e30f;
        if (r < TT) {
            uint4 raw = *(const uint4*)(qb + (size_t)r * 128);
            float v[8];
            unpack8(raw, v);
            float dot = 0.f;
#pragma unroll
            for (int j = 0; j < 8; ++j) dot = fmaf(v[j], ks[j], dot);
            s = dot * scale;
        }
        sv[i] = s;
        m = fmaxf(m, s);
    }
#pragma unroll
    for (int off = 1; off < 64; off <<= 1) m = fmaxf(m, __shfl_xor(m, off));
    float sum = 0.f;
#pragma unroll
    for (int i = 0; i < 6; ++i) {
        float ev = (sv[i] > -1e29f) ? expf(sv[i] - m) : 0.f;
        sv[i] = ev; sum += ev;
    }
#pragma unroll
    for (int off = 1; off < 64; off <<= 1) sum += __shfl_xor(sum, off);
    float inv = 1.f / sum;
#pragma unroll
    for (int i = 0; i < 6; ++i) {
        int r = lane + i * 64;
        if (r < TT) aw[r] = sv[i] * inv;
    }
    __syncthreads();
    // yv[b, h*16 + half*8 + j] = sum_r aw[r] * e[b,r,col]
    const int half = lane & 1, rs = lane >> 1;
    float acc[8] = {0.f,0.f,0.f,0.f,0.f,0.f,0.f,0.f};
    const bf16* ebase = e + (size_t)b * TT * 256 + h * 16 + half * 8;
#pragma unroll
    for (int i = 0; i < 12; ++i) {
        int r = rs + i * 32;
        if (r < TT) {
            uint4 raw = *(const uint4*)(ebase + (size_t)r * 256);
            float v[8];
            unpack8(raw, v);
            float a = aw[r];
#pragma unroll
            for (int j = 0; j < 8; ++j) acc[j] = fmaf(a, v[j], acc[j]);
        }
    }
#pragma unroll
    for (int off = 2; off < 64; off <<= 1)
#pragma unroll
        for (int j = 0; j < 8; ++j) acc[j] += __shfl_xor(acc[j], off);
    if (lane < 2) {
        float* op = yv + b * 256 + h * 16 + half * 8;
#pragma unroll
        for (int j = 0; j < 8; ++j) op[j] = acc[j];
    }
}

// ---------------- fused tail (weights staged in LDS) ----------------
__global__ __launch_bounds__(1024) void tail_kernel(
    const float* __restrict__ yv,
    const float* wm, const float* bm, const float* gm, const float* em,
    const float* wd1, const float* bd1, const float* gd1, const float* ed1,
    const float* wd2, const float* bd2, const float* gd2, const float* ed2,
    const float* wc, const float* bc, float* __restrict__ out)
{
    __shared__ float lds[12352];
    const int t = threadIdx.x;
    const int r = t & 63, cg = t >> 6;
    float* Xq  = lds;            // [64k][65]
    float* Wp  = lds + 4160;     // [128c][64k]
    float* Z1t = lds;            // [128c][64r]
    float* Wd1h = lds + 8192;    // [64c][64k]
    float* Z2t = lds;            // [64c][64r]
    float* Wd2 = lds + 4096;     // [32c][64k]
    float* Z3t = lds + 6144;     // [32c][64r]
    float* WcL = lds + 8192;     // [10c][32k]

    float acc1[8] = {0.f,0.f,0.f,0.f,0.f,0.f,0.f,0.f};
    const int c01 = cg * 8;
    for (int p = 0; p < 4; ++p) {
        __syncthreads();
        for (int i = t; i < 4096; i += 1024) {
            int kk = i & 63, rr = i >> 6;
            Xq[kk * 65 + rr] = yv[rr * 256 + p * 64 + kk];
        }
        {
            const float4* wm4 = (const float4*)wm;
            float4* Wp4 = (float4*)Wp;
            for (int i = t; i < 2048; i += 1024) {
                int kk4 = i & 15, c = i >> 4;
                Wp4[c * 16 + kk4] = wm4[c * 64 + p * 16 + kk4];
            }
        }
        __syncthreads();
#pragma unroll 4
        for (int k4 = 0; k4 < 16; ++k4) {
            float xv[4];
#pragma unroll
            for (int j = 0; j < 4; ++j) xv[j] = Xq[(k4 * 4 + j) * 65 + r];
#pragma unroll
            for (int c = 0; c < 8; ++c) {
                float4 w = *(const float4*)(Wp + (c01 + c) * 64 + k4 * 4);
                acc1[c] = fmaf(xv[0], w.x, acc1[c]);
                acc1[c] = fmaf(xv[1], w.y, acc1[c]);
                acc1[c] = fmaf(xv[2], w.z, acc1[c]);
                acc1[c] = fmaf(xv[3], w.w, acc1[c]);
            }
        }
    }
    float z1v[8];
#pragma unroll
    for (int c = 0; c < 8; ++c) {
        float v = acc1[c] + bm[c01 + c];
        float s = v, q = v * v;
#pragma unroll
        for (int off = 1; off < 64; off <<= 1) { s += __shfl_xor(s, off); q += __shfl_xor(q, off); }
        float mu = s * (1.f / 64.f), var = q * (1.f / 64.f) - mu * mu;
        z1v[c] = fmaxf((v - mu) * rsqrtf(var + 1e-5f) * gm[c01 + c] + em[c01 + c], 0.f);
    }
    __syncthreads();
#pragma unroll
    for (int c = 0; c < 8; ++c) Z1t[(c01 + c) * 64 + r] = z1v[c];
    float acc2[4] = {0.f, 0.f, 0.f, 0.f};
    const int c02 = cg * 4;
    for (int ph = 0; ph < 2; ++ph) {
        __syncthreads();
        {
            const float4* s4 = (const float4*)wd1;
            float4* d4 = (float4*)Wd1h;
            int kk4 = t & 15, c = t >> 4;
            d4[c * 16 + kk4] = s4[c * 32 + ph * 16 + kk4];
        }
        __syncthreads();
#pragma unroll 4
        for (int k4 = 0; k4 < 16; ++k4) {
            float xv[4];
#pragma unroll
            for (int j = 0; j < 4; ++j) xv[j] = Z1t[(ph * 64 + k4 * 4 + j) * 64 + r];
#pragma unroll
            for (int c = 0; c < 4; ++c) {
                float4 w = *(const float4*)(Wd1h + (c02 + c) * 64 + k4 * 4);
                acc2[c] = fmaf(xv[0], w.x, acc2[c]);
                acc2[c] = fmaf(xv[1], w.y, acc2[c]);
                acc2[c] = fmaf(xv[2], w.z, acc2[c]);
                acc2[c] = fmaf(xv[3], w.w, acc2[c]);
            }
        }
    }
    float z2v[4];
#pragma unroll
    for (int c = 0; c < 4; ++c) {
        float v = acc2[c] + bd1[c02 + c];
        float s = v, q = v * v;
#pragma unroll
        for (int off = 1; off < 64; off <<= 1) { s += __shfl_xor(s, off); q += __shfl_xor(q, off); }
        float mu = s * (1.f / 64.f), var = q * (1.f / 64.f) - mu * mu;
        z2v[c] = fmaxf((v - mu) * rsqrtf(var + 1e-5f) * gd1[c02 + c] + ed1[c02 + c], 0.f);
    }
    __syncthreads();
#pragma unroll
    for (int c = 0; c < 4; ++c) Z2t[(c02 + c) * 64 + r] = z2v[c];
    {
        const float4* s4 = (const float4*)wd2;
        float4* d4 = (float4*)Wd2;
        if (t < 512) d4[t] = s4[t];
    }
    __syncthreads();
    float acc3[2] = {0.f, 0.f};
    const int c03 = cg * 2;
#pragma unroll 4
    for (int k4 = 0; k4 < 16; ++k4) {
        float xv[4];
#pragma unroll
        for (int j = 0; j < 4; ++j) xv[j] = Z2t[(k4 * 4 + j) * 64 + r];
#pragma unroll
        for (int c = 0; c < 2; ++c) {
            float4 w = *(const float4*)(Wd2 + (c03 + c) * 64 + k4 * 4);
            acc3[c] = fmaf(xv[0], w.x, acc3[c]);
            acc3[c] = fmaf(xv[1], w.y, acc3[c]);
            acc3[c] = fmaf(xv[2], w.z, acc3[c]);
            acc3[c] = fmaf(xv[3], w.w, acc3[c]);
        }
    }
#pragma unroll
    for (int c = 0; c < 2; ++c) {
        float v = acc3[c] + bd2[c03 + c];
        float s = v, q = v * v;
#pragma unroll
        for (int off = 1; off < 64; off <<= 1) { s += __shfl_xor(s, off); q += __shfl_xor(q, off); }
        float mu = s * (1.f / 64.f), var = q * (1.f / 64.f) - mu * mu;
        Z3t[(c03 + c) * 64 + r] = fmaxf((v - mu) * rsqrtf(var + 1e-5f) * gd2[c03 + c] + ed2[c03 + c], 0.f);
    }
    if (t < 80) ((float4*)WcL)[t] = ((const float4*)wc)[t];
    __syncthreads();
    if (t < 640) {
        int rr = t / 10, c = t % 10;
        float s = bc[c];
#pragma unroll
        for (int kk = 0; kk < 32; ++kk) s = fmaf(Z3t[kk * 64 + rr], WcL[c * 32 + kk], s);
        out[t] = s;
    }
}

// ---------------- launch ----------------

extern "C" void kernel_launch(void* const* d_in, const int* in_sizes, int n_in,
                              void* d_out, int out_size, void* d_ws, size_t ws_size,
                              hipStream_t stream) {
    (void)in_sizes; (void)n_in; (void)out_size; (void)ws_size;
    const float* x  = (const float*)d_in[0];
    const int* pos  = (const int*)d_in[1];
    const float *w1 = (const float*)d_in[2],  *b1 = (const float*)d_in[3],
                *g1 = (const float*)d_in[4],  *e1 = (const float*)d_in[5];
    const float *w2 = (const float*)d_in[6],  *b2 = (const float*)d_in[7],
                *g2 = (const float*)d_in[8],  *e2 = (const float*)d_in[9];
    const float *w3 = (const float*)d_in[10], *b3 = (const float*)d_in[11],
                *g3 = (const float*)d_in[12], *e3 = (const float*)d_in[13];
    const float *ws1 = (const float*)d_in[14], *ws2 = (const float*)d_in[15];
    const float *wi = (const float*)d_in[16], *bi = (const float*)d_in[17],
                *gi = (const float*)d_in[18], *ei = (const float*)d_in[19];
    const float *wk = (const float*)d_in[20], *bk = (const float*)d_in[21];   // k before q!
    const float *wq = (const float*)d_in[22], *bq = (const float*)d_in[23];
    const float *wm = (const float*)d_in[24], *bm = (const float*)d_in[25],
                *gm = (const float*)d_in[26], *em = (const float*)d_in[27];
    const float *wd1 = (const float*)d_in[28], *bd1 = (const float*)d_in[29],
                *gd1 = (const float*)d_in[30], *ed1 = (const float*)d_in[31];
    const float *wd2 = (const float*)d_in[32], *bd2 = (const float*)d_in[33],
                *gd2 = (const float*)d_in[34], *ed2 = (const float*)d_in[35];
    const float *wc = (const float*)d_in[36], *bc = (const float*)d_in[37];
    float* out = (float*)d_out;

    char* w8 = (char*)d_ws;
    bf16*  actA   = (bf16*)(w8);                    // 11,960,320
    bf16*  actB   = (bf16*)(w8 + 11960320);         // 11,960,320
    bf16*  whi    = (bf16*)(w8 + 23920640);         //    278,528
    bf16*  wlo    = (bf16*)(w8 + 24199168);         //    278,528
    float* tab    = (float*)(w8 + 24477696);        //    435,200
    float* stats  = (float*)(w8 + 24912896);        //      8,192
    float* pooled = (float*)(w8 + 24921088);        //     65,536
    float* sebuf  = (float*)(w8 + 24986624);        //     65,536
    float* esum   = (float*)(w8 + 25052160);        //     65,536
    float* yvb    = (float*)(w8 + 25117696);        //     65,536

    prep_kernel<<<1105, 256, 0, stream>>>(stats, pooled, esum, w2, w3, wi, wq, whi, wlo, tab);
    // L1: 10 -> 64 -> Y1 = actB + stats1
    gemm_l1_kernel<<<365, 256, 0, stream>>>(x, w1, b1, actB, stats);
    // L2: 64 -> 128, fused BN1 -> Y2 = actA + stats2
    mfma_gemm<1, 64><<<dim3(365, 2), 256, 0, stream>>>(actB, whi, wlo, b2,
                                                       actA, 128, stats + 512, stats, g1, e1, nullptr);
    // L3: 128 -> 256, fused BN2 -> Y3 = actB + stats3
    mfma_gemm<1, 128><<<dim3(365, 4), 256, 0, stream>>>(actA, whi + 8192, wlo + 8192, b3,
                                                        actB, 256, stats + 1024, stats + 512, g2, e2, nullptr);
    // pool (fused BN3+relu) -> pooled; SE MLP -> sebuf
    pool_partial_kernel<<<dim3(64, 8), 256, 0, stream>>>(actB, stats + 1024, g3, e3, pooled);
    se_mlp_kernel<<<64, 256, 0, stream>>>(pooled, ws1, ws2, sebuf);
    // inconv: A = Y3 with fused BN3+relu+SE-residual -> Yi = actA + statsi
    mfma_gemm<2, 256><<<dim3(365, 4), 256, 0, stream>>>(actB, whi + 40960, wlo + 40960, bi,
                                                        actA, 256, stats + 1536, stats + 1024, g3, e3, sebuf);
    // bn_i + relu + PE -> e = actB
    bnrelu8_kernel<<<BT * 256 / 2048, 256, 0, stream>>>(actA, stats + 1536, gi, ei, actB, tab, pos);
    // esum over e
    esum_kernel<<<dim3(64, 8), 256, 0, stream>>>(actB, esum);
    // q projection only: 256 -> 128 -> q = actA (ld 128)
    mfma_gemm<0, 256><<<dim3(365, 2), 256, 0, stream>>>(actB, whi + 106496, wlo + 106496, bq,
                                                        actA, 128, nullptr, nullptr, nullptr, nullptr, nullptr);
    // attention: one wave per (b,h); ksum from esum.wk^T
    attn_kernel<<<dim3(64, 16), 64, 0, stream>>>(actA, actB, esum, wk, bk, yvb);
    // fused tail
    tail_kernel<<<1, 1024, 0, stream>>>(yvb, wm, bm, gm, em, wd1, bd1, gd1, ed1,
                                        wd2, bd2, gd2, ed2, wc, bc, out);
}